// Round 4
// baseline (938.955 us; speedup 1.0000x reference)
//
#include <hip/hip_runtime.h>
#include <math.h>

#define NNODES 100000
#define NEDGES 1600000
#define NIN 256
#define HID 128
#define NCLS 3
#define SCAN_BLK 256
#define SCAN_ELEMS 1024
#define SCAN_NB 98   // ceil(100000/1024)

__device__ __forceinline__ float lrelu(float x) { return x > 0.f ? x : 0.2f * x; }

__device__ __forceinline__ float waveReduceSum(float v) {
    #pragma unroll
    for (int o = 32; o > 0; o >>= 1) v += __shfl_xor(v, o, 64);
    return v;
}
__device__ __forceinline__ float waveReduceMax(float v) {
    #pragma unroll
    for (int o = 32; o > 0; o >>= 1) v = fmaxf(v, __shfl_xor(v, o, 64));
    return v;
}

// ---------------- CSR build ----------------

__global__ void k_count(const int* __restrict__ dst, int* __restrict__ counts) {
    int e = blockIdx.x * blockDim.x + threadIdx.x;
    if (e < NEDGES) atomicAdd(&counts[dst[e]], 1);
}

__global__ void k_scan1(const int* __restrict__ counts, int* __restrict__ offs,
                        int* __restrict__ partials) {
    __shared__ int sh[SCAN_BLK];
    int t = threadIdx.x, b = blockIdx.x;
    int base = b * SCAN_ELEMS + t * 4;
    int v[4]; int tot = 0;
    #pragma unroll
    for (int j = 0; j < 4; j++) {
        v[j] = (base + j < NNODES) ? counts[base + j] : 0;
        tot += v[j];
    }
    sh[t] = tot;
    __syncthreads();
    for (int o = 1; o < SCAN_BLK; o <<= 1) {
        int x = (t >= o) ? sh[t - o] : 0;
        __syncthreads();
        sh[t] += x;
        __syncthreads();
    }
    int excl = sh[t] - tot;
    if (t == SCAN_BLK - 1) partials[b] = sh[t];
    int r = excl;
    #pragma unroll
    for (int j = 0; j < 4; j++) {
        if (base + j < NNODES) offs[base + j] = r;
        r += v[j];
    }
}

__global__ void k_scan2(int* __restrict__ partials, int nb) {
    if (threadIdx.x == 0 && blockIdx.x == 0) {
        int run = 0;
        for (int i = 0; i < nb; i++) { int x = partials[i]; partials[i] = run; run += x; }
    }
}

__global__ void k_scan3(int* __restrict__ offs, const int* __restrict__ partials,
                        int* __restrict__ cursor) {
    int t = threadIdx.x, b = blockIdx.x;
    int add = partials[b];
    int base = b * SCAN_ELEMS + t * 4;
    #pragma unroll
    for (int j = 0; j < 4; j++) {
        int i = base + j;
        if (i < NNODES) { int o = offs[i] + add; offs[i] = o; cursor[i] = o; }
    }
    if (b == 0 && t == 0) offs[NNODES] = NEDGES;
}

__global__ void k_scatter(const int* __restrict__ src, const int* __restrict__ dst,
                          int* __restrict__ cursor, int* __restrict__ csr) {
    int e = blockIdx.x * blockDim.x + threadIdx.x;
    if (e < NEDGES) {
        int d = dst[e];
        int pos = atomicAdd(&cursor[d], 1);
        csr[pos] = src[e];
    }
}

// ---------------- GEMM: C[N x 128] = A[N x K] @ B[K x 128], fp32 ----------------

template<int K>
__global__ __launch_bounds__(256) void k_gemm(const float* __restrict__ A,
                                              const float* __restrict__ B,
                                              float* __restrict__ C) {
    const int BM = 128, BN = 128, BK = 32;
    __shared__ float As[BM][BK + 1];
    __shared__ float Bs[BK][BN];
    int tid = threadIdx.x;
    int tc = tid & 15, tr = tid >> 4;
    int row0 = blockIdx.x * BM;
    float acc[8][8];
    #pragma unroll
    for (int i = 0; i < 8; i++)
        #pragma unroll
        for (int j = 0; j < 8; j++) acc[i][j] = 0.f;

    for (int k0 = 0; k0 < K; k0 += BK) {
        #pragma unroll
        for (int p = 0; p < 4; p++) {
            int idx = tid + p * 256;
            // A tile: 128 rows x 8 float4 per row
            int ar = idx >> 3, ac = (idx & 7) * 4;
            float4 av = make_float4(0.f, 0.f, 0.f, 0.f);
            int grow = row0 + ar;
            if (grow < NNODES) av = *(const float4*)(A + (size_t)grow * K + k0 + ac);
            As[ar][ac + 0] = av.x; As[ar][ac + 1] = av.y;
            As[ar][ac + 2] = av.z; As[ar][ac + 3] = av.w;
            // B tile: 32 rows x 32 float4 per row
            int br = idx >> 5, bc = (idx & 31) * 4;
            float4 bv = *(const float4*)(B + (size_t)(k0 + br) * BN + bc);
            *(float4*)(&Bs[br][bc]) = bv;
        }
        __syncthreads();
        #pragma unroll
        for (int k = 0; k < BK; k++) {
            float a[8];
            #pragma unroll
            for (int i = 0; i < 8; i++) a[i] = As[tr * 8 + i][k];
            float4 b0 = *(const float4*)(&Bs[k][tc * 4]);
            float4 b1 = *(const float4*)(&Bs[k][64 + tc * 4]);
            float bb[8] = {b0.x, b0.y, b0.z, b0.w, b1.x, b1.y, b1.z, b1.w};
            #pragma unroll
            for (int i = 0; i < 8; i++)
                #pragma unroll
                for (int j = 0; j < 8; j++) acc[i][j] += a[i] * bb[j];
        }
        __syncthreads();
    }
    #pragma unroll
    for (int i = 0; i < 8; i++) {
        int grow = row0 + tr * 8 + i;
        if (grow < NNODES) {
            float4 v0 = make_float4(acc[i][0], acc[i][1], acc[i][2], acc[i][3]);
            float4 v1 = make_float4(acc[i][4], acc[i][5], acc[i][6], acc[i][7]);
            *(float4*)(C + (size_t)grow * 128 + tc * 4) = v0;
            *(float4*)(C + (size_t)grow * 128 + 64 + tc * 4) = v1;
        }
    }
}

// ---------------- per-node attention scores ----------------

__global__ void k_scores(const float* __restrict__ h, const float* __restrict__ a_src,
                         const float* __restrict__ a_dst, float* __restrict__ ssrc,
                         float* __restrict__ sdst) {
    int lane = threadIdx.x & 63;
    int node = (blockIdx.x * blockDim.x + threadIdx.x) >> 6;
    if (node >= NNODES) return;
    float v0 = h[(size_t)node * HID + lane];
    float v1 = h[(size_t)node * HID + 64 + lane];
    float s1 = v0 * a_src[lane] + v1 * a_src[64 + lane];
    float s2 = v0 * a_dst[lane] + v1 * a_dst[64 + lane];
    s1 = waveReduceSum(s1);
    s2 = waveReduceSum(s2);
    if (lane == 0) { ssrc[node] = s1; sdst[node] = s2; }
}

// ---------------- segment-softmax aggregation (wave per dst node) ----------------

__global__ void k_agg(const float* __restrict__ h, const float* __restrict__ ssrc,
                      const float* __restrict__ sdst, const int* __restrict__ offs,
                      const int* __restrict__ csr, const float* __restrict__ bias,
                      float* __restrict__ out, int do_relu) {
    int lane = threadIdx.x & 63;
    int node = (blockIdx.x * blockDim.x + threadIdx.x) >> 6;
    if (node >= NNODES) return;
    int beg = offs[node], end = offs[node + 1];
    float sd = sdst[node];
    float e_self = lrelu(ssrc[node] + sd);
    // pass 1: segment max (self-loop included analytically)
    float m = e_self;
    for (int base = beg; base < end; base += 64) {
        int j = base + lane;
        float e = -3.4e38f;
        if (j < end) e = lrelu(ssrc[csr[j]] + sd);
        e = waveReduceMax(e);
        m = fmaxf(m, e);
    }
    // pass 2: exp weights + weighted feature accumulation
    float wself = __expf(e_self - m);
    float acc0 = wself * h[(size_t)node * HID + lane];
    float acc1 = wself * h[(size_t)node * HID + 64 + lane];
    float den_lane = 0.f;
    for (int base = beg; base < end; base += 64) {
        int j = base + lane;
        int s = 0; float w = 0.f;
        if (j < end) {
            s = csr[j];
            w = __expf(lrelu(ssrc[s] + sd) - m);
        }
        den_lane += w;
        int cnt = min(64, end - base);
        for (int t = 0; t < cnt; ++t) {
            float wj = __shfl(w, t, 64);
            int sj = __shfl(s, t, 64);
            acc0 += wj * h[(size_t)sj * HID + lane];
            acc1 += wj * h[(size_t)sj * HID + 64 + lane];
        }
    }
    float den = wself + waveReduceSum(den_lane);
    float inv = 1.f / den;
    float r0 = acc0 * inv + bias[lane];
    float r1 = acc1 * inv + bias[64 + lane];
    if (do_relu) { r0 = fmaxf(r0, 0.f); r1 = fmaxf(r1, 0.f); }
    out[(size_t)node * HID + lane] = r0;
    out[(size_t)node * HID + 64 + lane] = r1;
}

// ---------------- final 128->3 matvec + softmax ----------------

__global__ void k_final(const float* __restrict__ h, const float* __restrict__ Wo,
                        const float* __restrict__ bo, float* __restrict__ out) {
    int lane = threadIdx.x & 63;
    int node = (blockIdx.x * blockDim.x + threadIdx.x) >> 6;
    if (node >= NNODES) return;
    float v0 = h[(size_t)node * HID + lane];
    float v1 = h[(size_t)node * HID + 64 + lane];
    float p0 = v0 * Wo[lane * NCLS + 0] + v1 * Wo[(64 + lane) * NCLS + 0];
    float p1 = v0 * Wo[lane * NCLS + 1] + v1 * Wo[(64 + lane) * NCLS + 1];
    float p2 = v0 * Wo[lane * NCLS + 2] + v1 * Wo[(64 + lane) * NCLS + 2];
    p0 = waveReduceSum(p0);
    p1 = waveReduceSum(p1);
    p2 = waveReduceSum(p2);
    if (lane == 0) {
        p0 += bo[0]; p1 += bo[1]; p2 += bo[2];
        float mm = fmaxf(p0, fmaxf(p1, p2));
        float e0 = __expf(p0 - mm), e1 = __expf(p1 - mm), e2 = __expf(p2 - mm);
        float inv = 1.f / (e0 + e1 + e2);
        out[(size_t)node * 3 + 0] = e0 * inv;
        out[(size_t)node * 3 + 1] = e1 * inv;
        out[(size_t)node * 3 + 2] = e2 * inv;
    }
}

// ---------------- launch ----------------

extern "C" void kernel_launch(void* const* d_in, const int* in_sizes, int n_in,
                              void* d_out, int out_size, void* d_ws, size_t ws_size,
                              hipStream_t stream) {
    const float* x   = (const float*)d_in[0];
    const int*   ei  = (const int*)d_in[1];
    const float* W1  = (const float*)d_in[2];
    const float* a1s = (const float*)d_in[3];
    const float* a1d = (const float*)d_in[4];
    const float* b1  = (const float*)d_in[5];
    const float* W2  = (const float*)d_in[6];
    const float* a2s = (const float*)d_in[7];
    const float* a2d = (const float*)d_in[8];
    const float* b2  = (const float*)d_in[9];
    const float* Wo  = (const float*)d_in[10];
    const float* bo  = (const float*)d_in[11];
    float* out = (float*)d_out;

    const int* esrc = ei;
    const int* edst = ei + NEDGES;

    char* ws = (char*)d_ws;
    size_t off = 0;
    auto alloc = [&](size_t bytes) -> void* {
        void* p = ws + off;
        off += (bytes + 255) & ~(size_t)255;
        return p;
    };
    float* buf0    = (float*)alloc((size_t)NNODES * HID * 4);
    float* buf1    = (float*)alloc((size_t)NNODES * HID * 4);
    float* ssrc    = (float*)alloc((size_t)NNODES * 4);
    float* sdst    = (float*)alloc((size_t)NNODES * 4);
    int*   offs    = (int*)alloc((size_t)(NNODES + 1) * 4);
    int*   cursor  = (int*)alloc((size_t)NNODES * 4);
    int*   partial = (int*)alloc(256 * 4);
    int*   csr     = (int*)alloc((size_t)NEDGES * 4);
    if (off > ws_size) return;  // workspace too small -> loud correctness failure

    // ---- CSR build (reused by both layers) ----
    hipMemsetAsync(cursor, 0, (size_t)NNODES * 4, stream);
    int egrid = (NEDGES + 255) / 256;
    k_count<<<egrid, 256, 0, stream>>>(edst, cursor);
    k_scan1<<<SCAN_NB, SCAN_BLK, 0, stream>>>(cursor, offs, partial);
    k_scan2<<<1, 64, 0, stream>>>(partial, SCAN_NB);
    k_scan3<<<SCAN_NB, SCAN_BLK, 0, stream>>>(offs, partial, cursor);
    k_scatter<<<egrid, 256, 0, stream>>>(esrc, edst, cursor, csr);

    int ggrid = (NNODES + 127) / 128;
    int wgrid = NNODES / 4;  // wave-per-node kernels, 4 waves/block

    // ---- layer 1 ----
    k_gemm<NIN><<<ggrid, 256, 0, stream>>>(x, W1, buf0);
    k_scores<<<wgrid, 256, 0, stream>>>(buf0, a1s, a1d, ssrc, sdst);
    k_agg<<<wgrid, 256, 0, stream>>>(buf0, ssrc, sdst, offs, csr, b1, buf1, 1);

    // ---- layer 2 ----
    k_gemm<HID><<<ggrid, 256, 0, stream>>>(buf1, W2, buf0);
    k_scores<<<wgrid, 256, 0, stream>>>(buf0, a2s, a2d, ssrc, sdst);
    k_agg<<<wgrid, 256, 0, stream>>>(buf0, ssrc, sdst, offs, csr, b2, buf1, 1);

    // ---- output head ----
    k_final<<<wgrid, 256, 0, stream>>>(buf1, Wo, bo, out);
}

// Round 7
// 738.575 us; speedup vs baseline: 1.2713x; 1.2713x over previous
//
#include <hip/hip_runtime.h>
#include <math.h>

#define NNODES 100000
#define NEDGES 1600000
#define NIN 256
#define HID 128
#define NCLS 3
#define SCAN_BLK 256
#define SCAN_ELEMS 1024
#define SCAN_NB 98   // ceil(100000/1024)

using f16x8 = __attribute__((ext_vector_type(8))) _Float16;
using f32x4 = __attribute__((ext_vector_type(4))) float;

__device__ __forceinline__ float lrelu(float x) { return x > 0.f ? x : 0.2f * x; }

__device__ __forceinline__ float waveReduceSum(float v) {
    #pragma unroll
    for (int o = 32; o > 0; o >>= 1) v += __shfl_xor(v, o, 64);
    return v;
}
__device__ __forceinline__ float waveReduceMax(float v) {
    #pragma unroll
    for (int o = 32; o > 0; o >>= 1) v = fmaxf(v, __shfl_xor(v, o, 64));
    return v;
}

// ---------------- CSR build ----------------

__global__ void k_count(const int* __restrict__ dst, int* __restrict__ counts) {
    int e = blockIdx.x * blockDim.x + threadIdx.x;
    if (e < NEDGES) atomicAdd(&counts[dst[e]], 1);
}

__global__ void k_scan1(const int* __restrict__ counts, int* __restrict__ offs,
                        int* __restrict__ partials) {
    __shared__ int sh[SCAN_BLK];
    int t = threadIdx.x, b = blockIdx.x;
    int base = b * SCAN_ELEMS + t * 4;
    int v[4]; int tot = 0;
    #pragma unroll
    for (int j = 0; j < 4; j++) {
        v[j] = (base + j < NNODES) ? counts[base + j] : 0;
        tot += v[j];
    }
    sh[t] = tot;
    __syncthreads();
    for (int o = 1; o < SCAN_BLK; o <<= 1) {
        int x = (t >= o) ? sh[t - o] : 0;
        __syncthreads();
        sh[t] += x;
        __syncthreads();
    }
    int excl = sh[t] - tot;
    if (t == SCAN_BLK - 1) partials[b] = sh[t];
    int r = excl;
    #pragma unroll
    for (int j = 0; j < 4; j++) {
        if (base + j < NNODES) offs[base + j] = r;
        r += v[j];
    }
}

__global__ void k_scan2(int* __restrict__ partials, int nb) {
    if (threadIdx.x == 0 && blockIdx.x == 0) {
        int run = 0;
        for (int i = 0; i < nb; i++) { int x = partials[i]; partials[i] = run; run += x; }
    }
}

__global__ void k_scan3(int* __restrict__ offs, const int* __restrict__ partials,
                        int* __restrict__ cursor) {
    int t = threadIdx.x, b = blockIdx.x;
    int add = partials[b];
    int base = b * SCAN_ELEMS + t * 4;
    #pragma unroll
    for (int j = 0; j < 4; j++) {
        int i = base + j;
        if (i < NNODES) { int o = offs[i] + add; offs[i] = o; cursor[i] = o; }
    }
    if (b == 0 && t == 0) offs[NNODES] = NEDGES;
}

__global__ void k_scatter(const int* __restrict__ src, const int* __restrict__ dst,
                          int* __restrict__ cursor, int* __restrict__ csr) {
    int e = blockIdx.x * blockDim.x + threadIdx.x;
    if (e < NEDGES) {
        int d = dst[e];
        int pos = atomicAdd(&cursor[d], 1);
        csr[pos] = src[e];
    }
}

// ---------------- weight prep: W[K x N] fp32 -> WT[N x K] fp16 ----------------

__global__ void k_prepT(const float* __restrict__ W, _Float16* __restrict__ WT,
                        int K, int N) {
    int i = blockIdx.x * blockDim.x + threadIdx.x;
    if (i < K * N) {
        int n = i / K, k = i - n * K;
        WT[i] = (_Float16)W[(size_t)k * N + n];
    }
}

// ---------------- MFMA GEMM: C[N x 128] = A[N x K](fp32) @ BT[128 x K](fp16) ----
// BM=64, BN=128, BK=32; 4 waves, each owns 32x64 (2x4 fragments of 16x16x32).
// A is converted fp32->fp16 during LDS staging (no separate conversion pass).
// LDS rows padded to 56 fp16 (112 B = 28 banks -> 2-way conflicts = free; keeps
// 16-B alignment for ds_*_b128).

#define LDP 56

template<int K>
__global__ __launch_bounds__(256) void k_gemm_mfma(const float* __restrict__ A,
                                                   const _Float16* __restrict__ BT,
                                                   float* __restrict__ C) {
    __shared__ __align__(16) _Float16 As[64][LDP];
    __shared__ __align__(16) _Float16 Bs[128][LDP];
    int tid = threadIdx.x;
    int lane = tid & 63, wid = tid >> 6;
    int wr = wid >> 1, wc = wid & 1;          // wave grid 2x2
    int row0 = blockIdx.x * 64;

    f32x4 acc[2][4];
    #pragma unroll
    for (int mi = 0; mi < 2; mi++)
        #pragma unroll
        for (int ni = 0; ni < 4; ni++) acc[mi][ni] = (f32x4){0.f, 0.f, 0.f, 0.f};

    int srow = tid >> 2;            // 0..63
    int skoff = (tid & 3) * 8;      // 0,8,16,24
    int l15 = lane & 15;
    int kblk = (lane >> 4) * 8;

    for (int k0 = 0; k0 < K; k0 += 32) {
        // ---- stage A (fp32 -> fp16) ----
        int grow = row0 + srow;
        float4 u0 = make_float4(0.f, 0.f, 0.f, 0.f), u1 = u0;
        if (grow < NNODES) {
            const float* ap = A + (size_t)grow * K + k0 + skoff;
            u0 = *(const float4*)ap;
            u1 = *(const float4*)(ap + 4);
        }
        f16x8 ah;
        ah[0] = (_Float16)u0.x; ah[1] = (_Float16)u0.y;
        ah[2] = (_Float16)u0.z; ah[3] = (_Float16)u0.w;
        ah[4] = (_Float16)u1.x; ah[5] = (_Float16)u1.y;
        ah[6] = (_Float16)u1.z; ah[7] = (_Float16)u1.w;
        *(f16x8*)&As[srow][skoff] = ah;
        // ---- stage B (already fp16, transposed) ----
        #pragma unroll
        for (int p = 0; p < 2; p++) {
            int n = p * 64 + srow;
            *(f16x8*)&Bs[n][skoff] = *(const f16x8*)(BT + (size_t)n * K + k0 + skoff);
        }
        __syncthreads();
        // ---- fragments + MFMA ----
        f16x8 af[2], bf[4];
        #pragma unroll
        for (int mi = 0; mi < 2; mi++)
            af[mi] = *(const f16x8*)&As[wr * 32 + mi * 16 + l15][kblk];
        #pragma unroll
        for (int ni = 0; ni < 4; ni++)
            bf[ni] = *(const f16x8*)&Bs[wc * 64 + ni * 16 + l15][kblk];
        #pragma unroll
        for (int mi = 0; mi < 2; mi++)
            #pragma unroll
            for (int ni = 0; ni < 4; ni++)
                acc[mi][ni] = __builtin_amdgcn_mfma_f32_16x16x32_f16(
                    af[mi], bf[ni], acc[mi][ni], 0, 0, 0);
        __syncthreads();
    }
    // ---- epilogue: C/D layout col=lane&15, row=(lane>>4)*4+j ----
    #pragma unroll
    for (int mi = 0; mi < 2; mi++) {
        #pragma unroll
        for (int ni = 0; ni < 4; ni++) {
            int r = row0 + wr * 32 + mi * 16 + ((lane >> 4) << 2);
            int c = wc * 64 + ni * 16 + l15;
            #pragma unroll
            for (int j = 0; j < 4; j++) {
                if (r + j < NNODES) C[(size_t)(r + j) * 128 + c] = acc[mi][ni][j];
            }
        }
    }
}

// ---------------- per-node attention scores ----------------

__global__ void k_scores(const float* __restrict__ h, const float* __restrict__ a_src,
                         const float* __restrict__ a_dst, float* __restrict__ ssrc,
                         float* __restrict__ sdst) {
    int lane = threadIdx.x & 63;
    int node = (blockIdx.x * blockDim.x + threadIdx.x) >> 6;
    if (node >= NNODES) return;
    float v0 = h[(size_t)node * HID + lane];
    float v1 = h[(size_t)node * HID + 64 + lane];
    float s1 = v0 * a_src[lane] + v1 * a_src[64 + lane];
    float s2 = v0 * a_dst[lane] + v1 * a_dst[64 + lane];
    s1 = waveReduceSum(s1);
    s2 = waveReduceSum(s2);
    if (lane == 0) { ssrc[node] = s1; sdst[node] = s2; }
}

// ---------------- segment-softmax aggregation (wave per dst node) ----------------

__global__ void k_agg(const float* __restrict__ h, const float* __restrict__ ssrc,
                      const float* __restrict__ sdst, const int* __restrict__ offs,
                      const int* __restrict__ csr, const float* __restrict__ bias,
                      float* __restrict__ out, int do_relu) {
    int lane = threadIdx.x & 63;
    int node = (blockIdx.x * blockDim.x + threadIdx.x) >> 6;
    if (node >= NNODES) return;
    int beg = offs[node], end = offs[node + 1];
    float sd = sdst[node];
    float e_self = lrelu(ssrc[node] + sd);
    // pass 1: segment max (self-loop included analytically)
    float m = e_self;
    for (int base = beg; base < end; base += 64) {
        int j = base + lane;
        float e = -3.4e38f;
        if (j < end) e = lrelu(ssrc[csr[j]] + sd);
        e = waveReduceMax(e);
        m = fmaxf(m, e);
    }
    // pass 2: exp weights + weighted feature accumulation
    float wself = __expf(e_self - m);
    float acc0 = wself * h[(size_t)node * HID + lane];
    float acc1 = wself * h[(size_t)node * HID + 64 + lane];
    float den_lane = 0.f;
    for (int base = beg; base < end; base += 64) {
        int j = base + lane;
        int s = 0; float w = 0.f;
        if (j < end) {
            s = csr[j];
            w = __expf(lrelu(ssrc[s] + sd) - m);
        }
        den_lane += w;
        int cnt = min(64, end - base);
        for (int t = 0; t < cnt; ++t) {
            float wj = __shfl(w, t, 64);
            int sj = __shfl(s, t, 64);
            acc0 += wj * h[(size_t)sj * HID + lane];
            acc1 += wj * h[(size_t)sj * HID + 64 + lane];
        }
    }
    float den = wself + waveReduceSum(den_lane);
    float inv = 1.f / den;
    float r0 = acc0 * inv + bias[lane];
    float r1 = acc1 * inv + bias[64 + lane];
    if (do_relu) { r0 = fmaxf(r0, 0.f); r1 = fmaxf(r1, 0.f); }
    out[(size_t)node * HID + lane] = r0;
    out[(size_t)node * HID + 64 + lane] = r1;
}

// ---------------- final 128->3 matvec + softmax ----------------

__global__ void k_final(const float* __restrict__ h, const float* __restrict__ Wo,
                        const float* __restrict__ bo, float* __restrict__ out) {
    int lane = threadIdx.x & 63;
    int node = (blockIdx.x * blockDim.x + threadIdx.x) >> 6;
    if (node >= NNODES) return;
    float v0 = h[(size_t)node * HID + lane];
    float v1 = h[(size_t)node * HID + 64 + lane];
    float p0 = v0 * Wo[lane * NCLS + 0] + v1 * Wo[(64 + lane) * NCLS + 0];
    float p1 = v0 * Wo[lane * NCLS + 1] + v1 * Wo[(64 + lane) * NCLS + 1];
    float p2 = v0 * Wo[lane * NCLS + 2] + v1 * Wo[(64 + lane) * NCLS + 2];
    p0 = waveReduceSum(p0);
    p1 = waveReduceSum(p1);
    p2 = waveReduceSum(p2);
    if (lane == 0) {
        p0 += bo[0]; p1 += bo[1]; p2 += bo[2];
        float mm = fmaxf(p0, fmaxf(p1, p2));
        float e0 = __expf(p0 - mm), e1 = __expf(p1 - mm), e2 = __expf(p2 - mm);
        float inv = 1.f / (e0 + e1 + e2);
        out[(size_t)node * 3 + 0] = e0 * inv;
        out[(size_t)node * 3 + 1] = e1 * inv;
        out[(size_t)node * 3 + 2] = e2 * inv;
    }
}

// ---------------- launch ----------------

extern "C" void kernel_launch(void* const* d_in, const int* in_sizes, int n_in,
                              void* d_out, int out_size, void* d_ws, size_t ws_size,
                              hipStream_t stream) {
    const float* x   = (const float*)d_in[0];
    const int*   ei  = (const int*)d_in[1];
    const float* W1  = (const float*)d_in[2];
    const float* a1s = (const float*)d_in[3];
    const float* a1d = (const float*)d_in[4];
    const float* b1  = (const float*)d_in[5];
    const float* W2  = (const float*)d_in[6];
    const float* a2s = (const float*)d_in[7];
    const float* a2d = (const float*)d_in[8];
    const float* b2  = (const float*)d_in[9];
    const float* Wo  = (const float*)d_in[10];
    const float* bo  = (const float*)d_in[11];
    float* out = (float*)d_out;

    const int* esrc = ei;
    const int* edst = ei + NEDGES;

    char* ws = (char*)d_ws;
    size_t off = 0;
    auto alloc = [&](size_t bytes) -> void* {
        void* p = ws + off;
        off += (bytes + 255) & ~(size_t)255;
        return p;
    };
    float*     buf0    = (float*)alloc((size_t)NNODES * HID * 4);
    float*     buf1    = (float*)alloc((size_t)NNODES * HID * 4);
    float*     ssrc    = (float*)alloc((size_t)NNODES * 4);
    float*     sdst    = (float*)alloc((size_t)NNODES * 4);
    int*       offs    = (int*)alloc((size_t)(NNODES + 1) * 4);
    int*       cursor  = (int*)alloc((size_t)NNODES * 4);
    int*       partial = (int*)alloc(256 * 4);
    int*       csr     = (int*)alloc((size_t)NEDGES * 4);
    _Float16*  w1t     = (_Float16*)alloc((size_t)HID * NIN * 2);
    _Float16*  w2t     = (_Float16*)alloc((size_t)HID * HID * 2);
    if (off > ws_size) return;  // workspace too small -> loud correctness failure

    // ---- weight prep (fp16, transposed) ----
    k_prepT<<<(NIN * HID + 255) / 256, 256, 0, stream>>>(W1, w1t, NIN, HID);
    k_prepT<<<(HID * HID + 255) / 256, 256, 0, stream>>>(W2, w2t, HID, HID);

    // ---- CSR build (reused by both layers) ----
    hipMemsetAsync(cursor, 0, (size_t)NNODES * 4, stream);
    int egrid = (NEDGES + 255) / 256;
    k_count<<<egrid, 256, 0, stream>>>(edst, cursor);
    k_scan1<<<SCAN_NB, SCAN_BLK, 0, stream>>>(cursor, offs, partial);
    k_scan2<<<1, 64, 0, stream>>>(partial, SCAN_NB);
    k_scan3<<<SCAN_NB, SCAN_BLK, 0, stream>>>(offs, partial, cursor);
    k_scatter<<<egrid, 256, 0, stream>>>(esrc, edst, cursor, csr);

    int mgrid = (NNODES + 63) / 64;   // 1563 blocks
    int wgrid = NNODES / 4;           // wave-per-node kernels, 4 waves/block

    // ---- layer 1 ----
    k_gemm_mfma<NIN><<<mgrid, 256, 0, stream>>>(x, w1t, buf0);
    k_scores<<<wgrid, 256, 0, stream>>>(buf0, a1s, a1d, ssrc, sdst);
    k_agg<<<wgrid, 256, 0, stream>>>(buf0, ssrc, sdst, offs, csr, b1, buf1, 1);

    // ---- layer 2 ----
    k_gemm_mfma<HID><<<mgrid, 256, 0, stream>>>(buf1, w2t, buf0);
    k_scores<<<wgrid, 256, 0, stream>>>(buf0, a2s, a2d, ssrc, sdst);
    k_agg<<<wgrid, 256, 0, stream>>>(buf0, ssrc, sdst, offs, csr, b2, buf1, 1);

    // ---- output head ----
    k_final<<<wgrid, 256, 0, stream>>>(buf1, Wo, bo, out);
}

// Round 10
// 619.645 us; speedup vs baseline: 1.5153x; 1.1919x over previous
//
#include <hip/hip_runtime.h>
#include <math.h>

#define NNODES 100000
#define NEDGES 1600000
#define NIN 256
#define HID 128
#define NCLS 3
#define SCAN_BLK 256
#define SCAN_ELEMS 1024
#define SCAN_NB 98   // ceil(100000/1024)

using f16x8 = __attribute__((ext_vector_type(8))) _Float16;
using f16x2 = __attribute__((ext_vector_type(2))) _Float16;
using f32x4 = __attribute__((ext_vector_type(4))) float;

__device__ __forceinline__ float lrelu(float x) { return x > 0.f ? x : 0.2f * x; }

__device__ __forceinline__ float waveReduceSum(float v) {
    #pragma unroll
    for (int o = 32; o > 0; o >>= 1) v += __shfl_xor(v, o, 64);
    return v;
}
__device__ __forceinline__ float waveReduceMax(float v) {
    #pragma unroll
    for (int o = 32; o > 0; o >>= 1) v = fmaxf(v, __shfl_xor(v, o, 64));
    return v;
}

__device__ __forceinline__ float2 unpack_h2(unsigned int u) {
    union { unsigned int u; f16x2 h; } cv; cv.u = u;
    return make_float2((float)cv.h[0], (float)cv.h[1]);
}
__device__ __forceinline__ unsigned int pack_h2(float x, float y) {
    union { unsigned int u; f16x2 h; } cv;
    cv.h[0] = (_Float16)x; cv.h[1] = (_Float16)y;
    return cv.u;
}

// ---------------- CSR build ----------------

__global__ void k_count(const int* __restrict__ dst, int* __restrict__ counts) {
    int e = blockIdx.x * blockDim.x + threadIdx.x;
    if (e < NEDGES) atomicAdd(&counts[dst[e]], 1);
}

__global__ void k_scan1(const int* __restrict__ counts, int* __restrict__ offs,
                        int* __restrict__ partials) {
    __shared__ int sh[SCAN_BLK];
    int t = threadIdx.x, b = blockIdx.x;
    int base = b * SCAN_ELEMS + t * 4;
    int v[4]; int tot = 0;
    #pragma unroll
    for (int j = 0; j < 4; j++) {
        v[j] = (base + j < NNODES) ? counts[base + j] : 0;
        tot += v[j];
    }
    sh[t] = tot;
    __syncthreads();
    for (int o = 1; o < SCAN_BLK; o <<= 1) {
        int x = (t >= o) ? sh[t - o] : 0;
        __syncthreads();
        sh[t] += x;
        __syncthreads();
    }
    int excl = sh[t] - tot;
    if (t == SCAN_BLK - 1) partials[b] = sh[t];
    int r = excl;
    #pragma unroll
    for (int j = 0; j < 4; j++) {
        if (base + j < NNODES) offs[base + j] = r;
        r += v[j];
    }
}

__global__ void k_scan2(int* __restrict__ partials, int nb) {
    if (threadIdx.x == 0 && blockIdx.x == 0) {
        int run = 0;
        for (int i = 0; i < nb; i++) { int x = partials[i]; partials[i] = run; run += x; }
    }
}

__global__ void k_scan3(int* __restrict__ offs, const int* __restrict__ partials,
                        int* __restrict__ cursor) {
    int t = threadIdx.x, b = blockIdx.x;
    int add = partials[b];
    int base = b * SCAN_ELEMS + t * 4;
    #pragma unroll
    for (int j = 0; j < 4; j++) {
        int i = base + j;
        if (i < NNODES) { int o = offs[i] + add; offs[i] = o; cursor[i] = o; }
    }
    if (b == 0 && t == 0) offs[NNODES] = NEDGES;
}

__global__ void k_scatter(const int* __restrict__ src, const int* __restrict__ dst,
                          int* __restrict__ cursor, int* __restrict__ csr) {
    int e = blockIdx.x * blockDim.x + threadIdx.x;
    if (e < NEDGES) {
        int d = dst[e];
        int pos = atomicAdd(&cursor[d], 1);
        csr[pos] = src[e];
    }
}

// ---------------- weight prep: W[K x N] fp32 -> WT[N x K] fp16 ----------------

__global__ void k_prepT(const float* __restrict__ W, _Float16* __restrict__ WT,
                        int K, int N) {
    int i = blockIdx.x * blockDim.x + threadIdx.x;
    if (i < K * N) {
        int n = i / K, k = i - n * K;
        WT[i] = (_Float16)W[(size_t)k * N + n];
    }
}

// ---- MFMA GEMM: C[N x 128](fp16) = A[N x K](fp32 or fp16) @ BT[128 x K](fp16) --
// BM=64, BN=128, BK=32; 4 waves, each owns 32x64 (2x4 fragments of 16x16x32).
// LDS rows padded to 56 fp16 (112 B = 28 banks -> 2-way conflicts = free; keeps
// 16-B alignment for ds_*_b128).

#define LDP 56

template<int K, bool IN16>
__global__ __launch_bounds__(256) void k_gemm_mfma(const void* __restrict__ Av,
                                                   const _Float16* __restrict__ BT,
                                                   _Float16* __restrict__ C) {
    __shared__ __align__(16) _Float16 As[64][LDP];
    __shared__ __align__(16) _Float16 Bs[128][LDP];
    int tid = threadIdx.x;
    int lane = tid & 63, wid = tid >> 6;
    int wr = wid >> 1, wc = wid & 1;          // wave grid 2x2
    int row0 = blockIdx.x * 64;

    f32x4 acc[2][4];
    #pragma unroll
    for (int mi = 0; mi < 2; mi++)
        #pragma unroll
        for (int ni = 0; ni < 4; ni++) acc[mi][ni] = (f32x4){0.f, 0.f, 0.f, 0.f};

    int srow = tid >> 2;            // 0..63
    int skoff = (tid & 3) * 8;      // 0,8,16,24
    int l15 = lane & 15;
    int kblk = (lane >> 4) * 8;

    for (int k0 = 0; k0 < K; k0 += 32) {
        // ---- stage A ----
        int grow = row0 + srow;
        f16x8 ah = (f16x8){0, 0, 0, 0, 0, 0, 0, 0};
        if (grow < NNODES) {
            if constexpr (IN16) {
                const _Float16* A = (const _Float16*)Av;
                ah = *(const f16x8*)(A + (size_t)grow * K + k0 + skoff);
            } else {
                const float* A = (const float*)Av;
                const float* ap = A + (size_t)grow * K + k0 + skoff;
                float4 u0 = *(const float4*)ap;
                float4 u1 = *(const float4*)(ap + 4);
                ah[0] = (_Float16)u0.x; ah[1] = (_Float16)u0.y;
                ah[2] = (_Float16)u0.z; ah[3] = (_Float16)u0.w;
                ah[4] = (_Float16)u1.x; ah[5] = (_Float16)u1.y;
                ah[6] = (_Float16)u1.z; ah[7] = (_Float16)u1.w;
            }
        }
        *(f16x8*)&As[srow][skoff] = ah;
        // ---- stage B (already fp16, transposed) ----
        #pragma unroll
        for (int p = 0; p < 2; p++) {
            int n = p * 64 + srow;
            *(f16x8*)&Bs[n][skoff] = *(const f16x8*)(BT + (size_t)n * K + k0 + skoff);
        }
        __syncthreads();
        // ---- fragments + MFMA ----
        f16x8 af[2], bf[4];
        #pragma unroll
        for (int mi = 0; mi < 2; mi++)
            af[mi] = *(const f16x8*)&As[wr * 32 + mi * 16 + l15][kblk];
        #pragma unroll
        for (int ni = 0; ni < 4; ni++)
            bf[ni] = *(const f16x8*)&Bs[wc * 64 + ni * 16 + l15][kblk];
        #pragma unroll
        for (int mi = 0; mi < 2; mi++)
            #pragma unroll
            for (int ni = 0; ni < 4; ni++)
                acc[mi][ni] = __builtin_amdgcn_mfma_f32_16x16x32_f16(
                    af[mi], bf[ni], acc[mi][ni], 0, 0, 0);
        __syncthreads();
    }
    // ---- epilogue: C/D layout col=lane&15, row=(lane>>4)*4+j; write fp16 ----
    #pragma unroll
    for (int mi = 0; mi < 2; mi++) {
        #pragma unroll
        for (int ni = 0; ni < 4; ni++) {
            int r = row0 + wr * 32 + mi * 16 + ((lane >> 4) << 2);
            int c = wc * 64 + ni * 16 + l15;
            #pragma unroll
            for (int j = 0; j < 4; j++) {
                if (r + j < NNODES)
                    C[(size_t)(r + j) * 128 + c] = (_Float16)acc[mi][ni][j];
            }
        }
    }
}

// ---------------- per-node attention scores (fp16 h, 2 cols/lane) --------------

__global__ void k_scores(const _Float16* __restrict__ h, const float* __restrict__ a_src,
                         const float* __restrict__ a_dst, float* __restrict__ ssrc,
                         float* __restrict__ sdst) {
    int lane = threadIdx.x & 63;
    int node = (blockIdx.x * blockDim.x + threadIdx.x) >> 6;
    if (node >= NNODES) return;
    const unsigned int* hrow = (const unsigned int*)h;
    float2 v = unpack_h2(hrow[(size_t)node * 64 + lane]);
    int c0 = lane * 2;
    float s1 = v.x * a_src[c0] + v.y * a_src[c0 + 1];
    float s2 = v.x * a_dst[c0] + v.y * a_dst[c0 + 1];
    s1 = waveReduceSum(s1);
    s2 = waveReduceSum(s2);
    if (lane == 0) { ssrc[node] = s1; sdst[node] = s2; }
}

// -------- segment-softmax aggregation (wave per dst node, fp16 h) --------------

__global__ void k_agg(const _Float16* __restrict__ h, const float* __restrict__ ssrc,
                      const float* __restrict__ sdst, const int* __restrict__ offs,
                      const int* __restrict__ csr, const float* __restrict__ bias,
                      _Float16* __restrict__ out, int do_relu) {
    int lane = threadIdx.x & 63;
    int node = (blockIdx.x * blockDim.x + threadIdx.x) >> 6;
    if (node >= NNODES) return;
    int beg = offs[node], end = offs[node + 1];
    float sd = sdst[node];
    float e_self = lrelu(ssrc[node] + sd);
    // pass 1: segment max (self-loop handled analytically)
    float m = e_self;
    for (int base = beg; base < end; base += 64) {
        int j = base + lane;
        float e = (j < end) ? lrelu(ssrc[csr[j]] + sd) : -3.4e38f;
        m = fmaxf(m, waveReduceMax(e));
    }
    // pass 2: exp weights + weighted feature accumulation (2 cols/lane)
    const unsigned int* hrow = (const unsigned int*)h;
    float wself = __expf(e_self - m);
    float2 hv = unpack_h2(hrow[(size_t)node * 64 + lane]);
    float a0[4] = {wself * hv.x, 0.f, 0.f, 0.f};
    float a1[4] = {wself * hv.y, 0.f, 0.f, 0.f};
    float den_lane = 0.f;
    for (int base = beg; base < end; base += 64) {
        int j = base + lane;
        int s = 0; float w = 0.f;
        if (j < end) {
            s = csr[j];
            w = __expf(lrelu(ssrc[s] + sd) - m);
        }
        den_lane += w;
        int cnt = min(64, end - base);
        int t = 0;
        for (; t + 4 <= cnt; t += 4) {
            float w0 = __shfl(w, t, 64),     w1 = __shfl(w, t + 1, 64);
            float w2 = __shfl(w, t + 2, 64), w3 = __shfl(w, t + 3, 64);
            int   s0 = __shfl(s, t, 64),     s1 = __shfl(s, t + 1, 64);
            int   s2 = __shfl(s, t + 2, 64), s3 = __shfl(s, t + 3, 64);
            unsigned int u0 = hrow[(size_t)s0 * 64 + lane];
            unsigned int u1 = hrow[(size_t)s1 * 64 + lane];
            unsigned int u2 = hrow[(size_t)s2 * 64 + lane];
            unsigned int u3 = hrow[(size_t)s3 * 64 + lane];
            float2 p0 = unpack_h2(u0), p1 = unpack_h2(u1);
            float2 p2 = unpack_h2(u2), p3 = unpack_h2(u3);
            a0[0] += w0 * p0.x; a1[0] += w0 * p0.y;
            a0[1] += w1 * p1.x; a1[1] += w1 * p1.y;
            a0[2] += w2 * p2.x; a1[2] += w2 * p2.y;
            a0[3] += w3 * p3.x; a1[3] += w3 * p3.y;
        }
        for (; t < cnt; ++t) {
            float wj = __shfl(w, t, 64);
            int sj = __shfl(s, t, 64);
            float2 p = unpack_h2(hrow[(size_t)sj * 64 + lane]);
            a0[0] += wj * p.x; a1[0] += wj * p.y;
        }
    }
    float den = wself + waveReduceSum(den_lane);
    float inv = 1.f / den;
    int c0 = lane * 2;
    float r0 = (a0[0] + a0[1] + a0[2] + a0[3]) * inv + bias[c0];
    float r1 = (a1[0] + a1[1] + a1[2] + a1[3]) * inv + bias[c0 + 1];
    if (do_relu) { r0 = fmaxf(r0, 0.f); r1 = fmaxf(r1, 0.f); }
    ((unsigned int*)out)[(size_t)node * 64 + lane] = pack_h2(r0, r1);
}

// ---------------- final 128->3 matvec + softmax (fp16 h) -----------------------

__global__ void k_final(const _Float16* __restrict__ h, const float* __restrict__ Wo,
                        const float* __restrict__ bo, float* __restrict__ out) {
    int lane = threadIdx.x & 63;
    int node = (blockIdx.x * blockDim.x + threadIdx.x) >> 6;
    if (node >= NNODES) return;
    const unsigned int* hrow = (const unsigned int*)h;
    float2 v = unpack_h2(hrow[(size_t)node * 64 + lane]);
    int c0 = lane * 2, c1 = lane * 2 + 1;
    float p0 = v.x * Wo[c0 * NCLS + 0] + v.y * Wo[c1 * NCLS + 0];
    float p1 = v.x * Wo[c0 * NCLS + 1] + v.y * Wo[c1 * NCLS + 1];
    float p2 = v.x * Wo[c0 * NCLS + 2] + v.y * Wo[c1 * NCLS + 2];
    p0 = waveReduceSum(p0);
    p1 = waveReduceSum(p1);
    p2 = waveReduceSum(p2);
    if (lane == 0) {
        p0 += bo[0]; p1 += bo[1]; p2 += bo[2];
        float mm = fmaxf(p0, fmaxf(p1, p2));
        float e0 = __expf(p0 - mm), e1 = __expf(p1 - mm), e2 = __expf(p2 - mm);
        float inv = 1.f / (e0 + e1 + e2);
        out[(size_t)node * 3 + 0] = e0 * inv;
        out[(size_t)node * 3 + 1] = e1 * inv;
        out[(size_t)node * 3 + 2] = e2 * inv;
    }
}

// ---------------- launch ----------------

extern "C" void kernel_launch(void* const* d_in, const int* in_sizes, int n_in,
                              void* d_out, int out_size, void* d_ws, size_t ws_size,
                              hipStream_t stream) {
    const float* x   = (const float*)d_in[0];
    const int*   ei  = (const int*)d_in[1];
    const float* W1  = (const float*)d_in[2];
    const float* a1s = (const float*)d_in[3];
    const float* a1d = (const float*)d_in[4];
    const float* b1  = (const float*)d_in[5];
    const float* W2  = (const float*)d_in[6];
    const float* a2s = (const float*)d_in[7];
    const float* a2d = (const float*)d_in[8];
    const float* b2  = (const float*)d_in[9];
    const float* Wo  = (const float*)d_in[10];
    const float* bo  = (const float*)d_in[11];
    float* out = (float*)d_out;

    const int* esrc = ei;
    const int* edst = ei + NEDGES;

    char* ws = (char*)d_ws;
    size_t off = 0;
    auto alloc = [&](size_t bytes) -> void* {
        void* p = ws + off;
        off += (bytes + 255) & ~(size_t)255;
        return p;
    };
    _Float16*  buf0    = (_Float16*)alloc((size_t)NNODES * HID * 2);
    _Float16*  buf1    = (_Float16*)alloc((size_t)NNODES * HID * 2);
    float*     ssrc    = (float*)alloc((size_t)NNODES * 4);
    float*     sdst    = (float*)alloc((size_t)NNODES * 4);
    int*       offs    = (int*)alloc((size_t)(NNODES + 1) * 4);
    int*       cursor  = (int*)alloc((size_t)NNODES * 4);
    int*       partial = (int*)alloc(256 * 4);
    int*       csr     = (int*)alloc((size_t)NEDGES * 4);
    _Float16*  w1t     = (_Float16*)alloc((size_t)HID * NIN * 2);
    _Float16*  w2t     = (_Float16*)alloc((size_t)HID * HID * 2);
    if (off > ws_size) return;  // workspace too small -> loud correctness failure

    // ---- weight prep (fp16, transposed) ----
    k_prepT<<<(NIN * HID + 255) / 256, 256, 0, stream>>>(W1, w1t, NIN, HID);
    k_prepT<<<(HID * HID + 255) / 256, 256, 0, stream>>>(W2, w2t, HID, HID);

    // ---- CSR build (reused by both layers) ----
    hipMemsetAsync(cursor, 0, (size_t)NNODES * 4, stream);
    int egrid = (NEDGES + 255) / 256;
    k_count<<<egrid, 256, 0, stream>>>(edst, cursor);
    k_scan1<<<SCAN_NB, SCAN_BLK, 0, stream>>>(cursor, offs, partial);
    k_scan2<<<1, 64, 0, stream>>>(partial, SCAN_NB);
    k_scan3<<<SCAN_NB, SCAN_BLK, 0, stream>>>(offs, partial, cursor);
    k_scatter<<<egrid, 256, 0, stream>>>(esrc, edst, cursor, csr);

    int mgrid = (NNODES + 63) / 64;   // 1563 blocks
    int wgrid = NNODES / 4;           // wave-per-node kernels, 4 waves/block

    // ---- layer 1 ----
    k_gemm_mfma<NIN, false><<<mgrid, 256, 0, stream>>>(x, w1t, buf0);
    k_scores<<<wgrid, 256, 0, stream>>>(buf0, a1s, a1d, ssrc, sdst);
    k_agg<<<wgrid, 256, 0, stream>>>(buf0, ssrc, sdst, offs, csr, b1, buf1, 1);

    // ---- layer 2 ----
    k_gemm_mfma<HID, true><<<mgrid, 256, 0, stream>>>(buf1, w2t, buf0);
    k_scores<<<wgrid, 256, 0, stream>>>(buf0, a2s, a2d, ssrc, sdst);
    k_agg<<<wgrid, 256, 0, stream>>>(buf0, ssrc, sdst, offs, csr, b2, buf1, 1);

    // ---- output head ----
    k_final<<<wgrid, 256, 0, stream>>>(buf1, Wo, bo, out);
}

// Round 11
// 591.577 us; speedup vs baseline: 1.5872x; 1.0474x over previous
//
#include <hip/hip_runtime.h>
#include <math.h>

#define NNODES 100000
#define NEDGES 1600000
#define NIN 256
#define HID 128
#define NCLS 3

// ---- bucket-sort CSR build parameters ----
#define NB   391      // ceil(NNODES/256) buckets of 256 nodes
#define NBLK 200      // pass-A blocks
#define EPB  8000     // edges per block (NBLK*EPB == NEDGES)
#define CB   (NB*NBLK)

using f16x8 = __attribute__((ext_vector_type(8))) _Float16;
using f16x2 = __attribute__((ext_vector_type(2))) _Float16;
using f32x4 = __attribute__((ext_vector_type(4))) float;

__device__ __forceinline__ float lrelu(float x) { return x > 0.f ? x : 0.2f * x; }

__device__ __forceinline__ float waveReduceSum(float v) {
    #pragma unroll
    for (int o = 32; o > 0; o >>= 1) v += __shfl_xor(v, o, 64);
    return v;
}
__device__ __forceinline__ float waveReduceMax(float v) {
    #pragma unroll
    for (int o = 32; o > 0; o >>= 1) v = fmaxf(v, __shfl_xor(v, o, 64));
    return v;
}

__device__ __forceinline__ float2 unpack_h2(unsigned int u) {
    union { unsigned int u; f16x2 h; } cv; cv.u = u;
    return make_float2((float)cv.h[0], (float)cv.h[1]);
}
__device__ __forceinline__ unsigned int pack_h2(float x, float y) {
    union { unsigned int u; f16x2 h; } cv;
    cv.h[0] = (_Float16)x; cv.h[1] = (_Float16)y;
    return cv.u;
}

// ---------------- CSR build: two-level bucket sort ----------------
// k_hist0: per-block histogram over NB buckets (bucket = dst>>8)

__global__ __launch_bounds__(256) void k_hist0(const int* __restrict__ dst,
                                               int* __restrict__ counts) {
    __shared__ int h[NB];
    int blk = blockIdx.x, t = threadIdx.x;
    for (int b = t; b < NB; b += 256) h[b] = 0;
    __syncthreads();
    int e0 = blk * EPB;
    for (int i = t; i < EPB; i += 256)
        atomicAdd(&h[dst[e0 + i] >> 8], 1);
    __syncthreads();
    for (int b = t; b < NB; b += 256) counts[b * NBLK + blk] = h[b];  // bucket-major
}

// k_scanA: exclusive scan of counts[CB] -> base[CB] (+sentinel)

__global__ void k_scanA(const int* __restrict__ counts, int* __restrict__ base,
                        int* __restrict__ offs) {
    __shared__ int sh[1024];
    int t = threadIdx.x;
    const int C = (CB + 1023) / 1024;
    int s0 = t * C, s1 = min(s0 + C, CB);
    int tot = 0;
    for (int i = s0; i < s1; i++) tot += counts[i];
    sh[t] = tot;
    __syncthreads();
    for (int o = 1; o < 1024; o <<= 1) {
        int x = (t >= o) ? sh[t - o] : 0;
        __syncthreads();
        sh[t] += x;
        __syncthreads();
    }
    int run = sh[t] - tot;
    for (int i = s0; i < s1; i++) { int c = counts[i]; base[i] = run; run += c; }
    if (t == 0) { base[CB] = NEDGES; offs[NNODES] = NEDGES; }
}

// k_passA: scatter (src,dst) pairs into per-(bucket,block) sequential streams

__global__ __launch_bounds__(256) void k_passA(const int* __restrict__ src,
                                               const int* __restrict__ dst,
                                               const int* __restrict__ base,
                                               uint2* __restrict__ pairs) {
    __shared__ int cur[NB];
    int blk = blockIdx.x, t = threadIdx.x;
    for (int b = t; b < NB; b += 256) cur[b] = base[b * NBLK + blk];
    __syncthreads();
    int e0 = blk * EPB;
    for (int i = t; i < EPB; i += 256) {
        int s = src[e0 + i], d = dst[e0 + i];
        int p = atomicAdd(&cur[d >> 8], 1);
        pairs[p] = make_uint2((unsigned)s, (unsigned)d);
    }
}

// k_passB: per bucket, local histogram+scan -> offs + csr (L2-local scatter)

__global__ __launch_bounds__(256) void k_passB(const uint2* __restrict__ pairs,
                                               const int* __restrict__ base,
                                               int* __restrict__ offs,
                                               int* __restrict__ csr) {
    __shared__ int cnt[256], exc[256], cur[256];
    int b = blockIdx.x, t = threadIdx.x;
    int node0 = b << 8;
    int beg  = base[b * NBLK];          // bucket-major scan => contiguous range
    int endp = base[(b + 1) * NBLK];
    cnt[t] = 0;
    __syncthreads();
    for (int i = beg + t; i < endp; i += 256)
        atomicAdd(&cnt[pairs[i].y - node0], 1);
    __syncthreads();
    int v = cnt[t];
    exc[t] = v;
    __syncthreads();
    for (int o = 1; o < 256; o <<= 1) {
        int x = (t >= o) ? exc[t - o] : 0;
        __syncthreads();
        exc[t] += x;
        __syncthreads();
    }
    int e = exc[t] - v;
    if (node0 + t < NNODES) offs[node0 + t] = beg + e;
    cur[t] = beg + e;
    __syncthreads();
    for (int i = beg + t; i < endp; i += 256) {
        uint2 pr = pairs[i];
        int p = atomicAdd(&cur[pr.y - node0], 1);
        csr[p] = (int)pr.x;
    }
}

// ---------------- weight prep: W[K x N] fp32 -> WT[N x K] fp16 ----------------

__global__ void k_prepT(const float* __restrict__ W, _Float16* __restrict__ WT,
                        int K, int N) {
    int i = blockIdx.x * blockDim.x + threadIdx.x;
    if (i < K * N) {
        int n = i / K, k = i - n * K;
        WT[i] = (_Float16)W[(size_t)k * N + n];
    }
}

// ---- MFMA GEMM: C[N x 128](fp16) = A[N x K](fp32 or fp16) @ BT[128 x K](fp16) --

#define LDP 56

template<int K, bool IN16>
__global__ __launch_bounds__(256) void k_gemm_mfma(const void* __restrict__ Av,
                                                   const _Float16* __restrict__ BT,
                                                   _Float16* __restrict__ C) {
    __shared__ __align__(16) _Float16 As[64][LDP];
    __shared__ __align__(16) _Float16 Bs[128][LDP];
    int tid = threadIdx.x;
    int lane = tid & 63, wid = tid >> 6;
    int wr = wid >> 1, wc = wid & 1;          // wave grid 2x2
    int row0 = blockIdx.x * 64;

    f32x4 acc[2][4];
    #pragma unroll
    for (int mi = 0; mi < 2; mi++)
        #pragma unroll
        for (int ni = 0; ni < 4; ni++) acc[mi][ni] = (f32x4){0.f, 0.f, 0.f, 0.f};

    int srow = tid >> 2;            // 0..63
    int skoff = (tid & 3) * 8;      // 0,8,16,24
    int l15 = lane & 15;
    int kblk = (lane >> 4) * 8;

    for (int k0 = 0; k0 < K; k0 += 32) {
        int grow = row0 + srow;
        f16x8 ah = (f16x8){0, 0, 0, 0, 0, 0, 0, 0};
        if (grow < NNODES) {
            if constexpr (IN16) {
                const _Float16* A = (const _Float16*)Av;
                ah = *(const f16x8*)(A + (size_t)grow * K + k0 + skoff);
            } else {
                const float* A = (const float*)Av;
                const float* ap = A + (size_t)grow * K + k0 + skoff;
                float4 u0 = *(const float4*)ap;
                float4 u1 = *(const float4*)(ap + 4);
                ah[0] = (_Float16)u0.x; ah[1] = (_Float16)u0.y;
                ah[2] = (_Float16)u0.z; ah[3] = (_Float16)u0.w;
                ah[4] = (_Float16)u1.x; ah[5] = (_Float16)u1.y;
                ah[6] = (_Float16)u1.z; ah[7] = (_Float16)u1.w;
            }
        }
        *(f16x8*)&As[srow][skoff] = ah;
        #pragma unroll
        for (int p = 0; p < 2; p++) {
            int n = p * 64 + srow;
            *(f16x8*)&Bs[n][skoff] = *(const f16x8*)(BT + (size_t)n * K + k0 + skoff);
        }
        __syncthreads();
        f16x8 af[2], bf[4];
        #pragma unroll
        for (int mi = 0; mi < 2; mi++)
            af[mi] = *(const f16x8*)&As[wr * 32 + mi * 16 + l15][kblk];
        #pragma unroll
        for (int ni = 0; ni < 4; ni++)
            bf[ni] = *(const f16x8*)&Bs[wc * 64 + ni * 16 + l15][kblk];
        #pragma unroll
        for (int mi = 0; mi < 2; mi++)
            #pragma unroll
            for (int ni = 0; ni < 4; ni++)
                acc[mi][ni] = __builtin_amdgcn_mfma_f32_16x16x32_f16(
                    af[mi], bf[ni], acc[mi][ni], 0, 0, 0);
        __syncthreads();
    }
    #pragma unroll
    for (int mi = 0; mi < 2; mi++) {
        #pragma unroll
        for (int ni = 0; ni < 4; ni++) {
            int r = row0 + wr * 32 + mi * 16 + ((lane >> 4) << 2);
            int c = wc * 64 + ni * 16 + l15;
            #pragma unroll
            for (int j = 0; j < 4; j++) {
                if (r + j < NNODES)
                    C[(size_t)(r + j) * 128 + c] = (_Float16)acc[mi][ni][j];
            }
        }
    }
}

// ---------------- per-node attention scores (fp16 h, 2 cols/lane) --------------

__global__ void k_scores(const _Float16* __restrict__ h, const float* __restrict__ a_src,
                         const float* __restrict__ a_dst, float* __restrict__ ssrc,
                         float* __restrict__ sdst) {
    int lane = threadIdx.x & 63;
    int node = (blockIdx.x * blockDim.x + threadIdx.x) >> 6;
    if (node >= NNODES) return;
    const unsigned int* hrow = (const unsigned int*)h;
    float2 v = unpack_h2(hrow[(size_t)node * 64 + lane]);
    int c0 = lane * 2;
    float s1 = v.x * a_src[c0] + v.y * a_src[c0 + 1];
    float s2 = v.x * a_dst[c0] + v.y * a_dst[c0 + 1];
    s1 = waveReduceSum(s1);
    s2 = waveReduceSum(s2);
    if (lane == 0) { ssrc[node] = s1; sdst[node] = s2; }
}

// -------- segment-softmax aggregation (wave per dst node, fp16 h) --------------

__global__ void k_agg(const _Float16* __restrict__ h, const float* __restrict__ ssrc,
                      const float* __restrict__ sdst, const int* __restrict__ offs,
                      const int* __restrict__ csr, const float* __restrict__ bias,
                      _Float16* __restrict__ out, int do_relu) {
    int lane = threadIdx.x & 63;
    int node = (blockIdx.x * blockDim.x + threadIdx.x) >> 6;
    if (node >= NNODES) return;
    int beg = offs[node], end = offs[node + 1];
    float sd = sdst[node];
    float e_self = lrelu(ssrc[node] + sd);
    float m = e_self;
    for (int base = beg; base < end; base += 64) {
        int j = base + lane;
        float e = (j < end) ? lrelu(ssrc[csr[j]] + sd) : -3.4e38f;
        m = fmaxf(m, waveReduceMax(e));
    }
    const unsigned int* hrow = (const unsigned int*)h;
    float wself = __expf(e_self - m);
    float2 hv = unpack_h2(hrow[(size_t)node * 64 + lane]);
    float a0[4] = {wself * hv.x, 0.f, 0.f, 0.f};
    float a1[4] = {wself * hv.y, 0.f, 0.f, 0.f};
    float den_lane = 0.f;
    for (int base = beg; base < end; base += 64) {
        int j = base + lane;
        int s = 0; float w = 0.f;
        if (j < end) {
            s = csr[j];
            w = __expf(lrelu(ssrc[s] + sd) - m);
        }
        den_lane += w;
        int cnt = min(64, end - base);
        int t = 0;
        for (; t + 4 <= cnt; t += 4) {
            float w0 = __shfl(w, t, 64),     w1 = __shfl(w, t + 1, 64);
            float w2 = __shfl(w, t + 2, 64), w3 = __shfl(w, t + 3, 64);
            int   s0 = __shfl(s, t, 64),     s1 = __shfl(s, t + 1, 64);
            int   s2 = __shfl(s, t + 2, 64), s3 = __shfl(s, t + 3, 64);
            unsigned int u0 = hrow[(size_t)s0 * 64 + lane];
            unsigned int u1 = hrow[(size_t)s1 * 64 + lane];
            unsigned int u2 = hrow[(size_t)s2 * 64 + lane];
            unsigned int u3 = hrow[(size_t)s3 * 64 + lane];
            float2 p0 = unpack_h2(u0), p1 = unpack_h2(u1);
            float2 p2 = unpack_h2(u2), p3 = unpack_h2(u3);
            a0[0] += w0 * p0.x; a1[0] += w0 * p0.y;
            a0[1] += w1 * p1.x; a1[1] += w1 * p1.y;
            a0[2] += w2 * p2.x; a1[2] += w2 * p2.y;
            a0[3] += w3 * p3.x; a1[3] += w3 * p3.y;
        }
        for (; t < cnt; ++t) {
            float wj = __shfl(w, t, 64);
            int sj = __shfl(s, t, 64);
            float2 p = unpack_h2(hrow[(size_t)sj * 64 + lane]);
            a0[0] += wj * p.x; a1[0] += wj * p.y;
        }
    }
    float den = wself + waveReduceSum(den_lane);
    float inv = 1.f / den;
    int c0 = lane * 2;
    float r0 = (a0[0] + a0[1] + a0[2] + a0[3]) * inv + bias[c0];
    float r1 = (a1[0] + a1[1] + a1[2] + a1[3]) * inv + bias[c0 + 1];
    if (do_relu) { r0 = fmaxf(r0, 0.f); r1 = fmaxf(r1, 0.f); }
    ((unsigned int*)out)[(size_t)node * 64 + lane] = pack_h2(r0, r1);
}

// ---------------- final 128->3 matvec + softmax (fp16 h) -----------------------

__global__ void k_final(const _Float16* __restrict__ h, const float* __restrict__ Wo,
                        const float* __restrict__ bo, float* __restrict__ out) {
    int lane = threadIdx.x & 63;
    int node = (blockIdx.x * blockDim.x + threadIdx.x) >> 6;
    if (node >= NNODES) return;
    const unsigned int* hrow = (const unsigned int*)h;
    float2 v = unpack_h2(hrow[(size_t)node * 64 + lane]);
    int c0 = lane * 2, c1 = lane * 2 + 1;
    float p0 = v.x * Wo[c0 * NCLS + 0] + v.y * Wo[c1 * NCLS + 0];
    float p1 = v.x * Wo[c0 * NCLS + 1] + v.y * Wo[c1 * NCLS + 1];
    float p2 = v.x * Wo[c0 * NCLS + 2] + v.y * Wo[c1 * NCLS + 2];
    p0 = waveReduceSum(p0);
    p1 = waveReduceSum(p1);
    p2 = waveReduceSum(p2);
    if (lane == 0) {
        p0 += bo[0]; p1 += bo[1]; p2 += bo[2];
        float mm = fmaxf(p0, fmaxf(p1, p2));
        float e0 = __expf(p0 - mm), e1 = __expf(p1 - mm), e2 = __expf(p2 - mm);
        float inv = 1.f / (e0 + e1 + e2);
        out[(size_t)node * 3 + 0] = e0 * inv;
        out[(size_t)node * 3 + 1] = e1 * inv;
        out[(size_t)node * 3 + 2] = e2 * inv;
    }
}

// ---------------- launch ----------------

extern "C" void kernel_launch(void* const* d_in, const int* in_sizes, int n_in,
                              void* d_out, int out_size, void* d_ws, size_t ws_size,
                              hipStream_t stream) {
    const float* x   = (const float*)d_in[0];
    const int*   ei  = (const int*)d_in[1];
    const float* W1  = (const float*)d_in[2];
    const float* a1s = (const float*)d_in[3];
    const float* a1d = (const float*)d_in[4];
    const float* b1  = (const float*)d_in[5];
    const float* W2  = (const float*)d_in[6];
    const float* a2s = (const float*)d_in[7];
    const float* a2d = (const float*)d_in[8];
    const float* b2  = (const float*)d_in[9];
    const float* Wo  = (const float*)d_in[10];
    const float* bo  = (const float*)d_in[11];
    float* out = (float*)d_out;

    const int* esrc = ei;
    const int* edst = ei + NEDGES;

    char* ws = (char*)d_ws;
    size_t off = 0;
    auto alloc = [&](size_t bytes) -> void* {
        void* p = ws + off;
        off += (bytes + 255) & ~(size_t)255;
        return p;
    };
    _Float16*  buf0    = (_Float16*)alloc((size_t)NNODES * HID * 2);
    _Float16*  buf1    = (_Float16*)alloc((size_t)NNODES * HID * 2);
    float*     ssrc    = (float*)alloc((size_t)NNODES * 4);
    float*     sdst    = (float*)alloc((size_t)NNODES * 4);
    int*       offs    = (int*)alloc((size_t)(NNODES + 1) * 4);
    int*       counts  = (int*)alloc((size_t)CB * 4);
    int*       base    = (int*)alloc((size_t)(CB + 1) * 4);
    uint2*     pairs   = (uint2*)alloc((size_t)NEDGES * 8);
    int*       csr     = (int*)alloc((size_t)NEDGES * 4);
    _Float16*  w1t     = (_Float16*)alloc((size_t)HID * NIN * 2);
    _Float16*  w2t     = (_Float16*)alloc((size_t)HID * HID * 2);
    if (off > ws_size) return;  // workspace too small -> loud correctness failure

    // ---- weight prep (fp16, transposed) ----
    k_prepT<<<(NIN * HID + 255) / 256, 256, 0, stream>>>(W1, w1t, NIN, HID);
    k_prepT<<<(HID * HID + 255) / 256, 256, 0, stream>>>(W2, w2t, HID, HID);

    // ---- CSR build via two-level bucket sort ----
    k_hist0<<<NBLK, 256, 0, stream>>>(edst, counts);
    k_scanA<<<1, 1024, 0, stream>>>(counts, base, offs);
    k_passA<<<NBLK, 256, 0, stream>>>(esrc, edst, base, pairs);
    k_passB<<<NB, 256, 0, stream>>>(pairs, base, offs, csr);

    int mgrid = (NNODES + 63) / 64;   // 1563 blocks
    int wgrid = NNODES / 4;           // wave-per-node kernels, 4 waves/block

    // ---- layer 1 ----
    k_gemm_mfma<NIN, false><<<mgrid, 256, 0, stream>>>(x, w1t, buf0);
    k_scores<<<wgrid, 256, 0, stream>>>(buf0, a1s, a1d, ssrc, sdst);
    k_agg<<<wgrid, 256, 0, stream>>>(buf0, ssrc, sdst, offs, csr, b1, buf1, 1);

    // ---- layer 2 ----
    k_gemm_mfma<HID, true><<<mgrid, 256, 0, stream>>>(buf1, w2t, buf0);
    k_scores<<<wgrid, 256, 0, stream>>>(buf0, a2s, a2d, ssrc, sdst);
    k_agg<<<wgrid, 256, 0, stream>>>(buf0, ssrc, sdst, offs, csr, b2, buf1, 1);

    // ---- output head ----
    k_final<<<wgrid, 256, 0, stream>>>(buf1, Wo, bo, out);
}

// Round 14
// 474.400 us; speedup vs baseline: 1.9792x; 1.2470x over previous
//
#include <hip/hip_runtime.h>
#include <math.h>

#define NNODES 100000
#define NEDGES 1600000
#define NIN 256
#define HID 128
#define NCLS 3

// ---- bucket-sort CSR build parameters ----
#define NB   391      // ceil(NNODES/256) buckets of 256 nodes
#define NBLK 200      // pass-A blocks
#define EPB  8000     // edges per block (NBLK*EPB == NEDGES)
#define CB   (NB*NBLK)
#define SC_BLKS 77    // ceil(CB/1024)

using f16x8 = __attribute__((ext_vector_type(8))) _Float16;
using f16x2 = __attribute__((ext_vector_type(2))) _Float16;
using f32x4 = __attribute__((ext_vector_type(4))) float;

__device__ __forceinline__ float lrelu(float x) { return x > 0.f ? x : 0.2f * x; }

__device__ __forceinline__ float waveReduceSum(float v) {
    #pragma unroll
    for (int o = 32; o > 0; o >>= 1) v += __shfl_xor(v, o, 64);
    return v;
}
__device__ __forceinline__ float waveReduceMax(float v) {
    #pragma unroll
    for (int o = 32; o > 0; o >>= 1) v = fmaxf(v, __shfl_xor(v, o, 64));
    return v;
}

__device__ __forceinline__ float2 unpack_h2(unsigned int u) {
    union { unsigned int u; f16x2 h; } cv; cv.u = u;
    return make_float2((float)cv.h[0], (float)cv.h[1]);
}
__device__ __forceinline__ unsigned int pack_h2(float x, float y) {
    union { unsigned int u; f16x2 h; } cv;
    cv.h[0] = (_Float16)x; cv.h[1] = (_Float16)y;
    return cv.u;
}

// ---------------- CSR build: two-level bucket sort ----------------
// k_hist0: per-block histogram over NB buckets (bucket = dst>>8)

__global__ __launch_bounds__(256) void k_hist0(const int* __restrict__ dst,
                                               int* __restrict__ counts) {
    __shared__ int h[NB];
    int blk = blockIdx.x, t = threadIdx.x;
    for (int b = t; b < NB; b += 256) h[b] = 0;
    __syncthreads();
    int e0 = blk * EPB;
    for (int i = t; i < EPB; i += 256)
        atomicAdd(&h[dst[e0 + i] >> 8], 1);
    __syncthreads();
    for (int b = t; b < NB; b += 256) counts[b * NBLK + blk] = h[b];  // bucket-major
}

// hierarchical exclusive scan of counts[CB] -> base[CB]  (3 kernels, parallel)

__global__ __launch_bounds__(256) void k_sc1(const int* __restrict__ counts,
                                             int* __restrict__ base,
                                             int* __restrict__ partials) {
    __shared__ int sh[256];
    int blk = blockIdx.x, t = threadIdx.x;
    int i0 = blk * 1024 + t * 4;
    int v[4]; int tot = 0;
    #pragma unroll
    for (int j = 0; j < 4; j++) {
        v[j] = (i0 + j < CB) ? counts[i0 + j] : 0;
        tot += v[j];
    }
    sh[t] = tot;
    __syncthreads();
    for (int o = 1; o < 256; o <<= 1) {
        int x = (t >= o) ? sh[t - o] : 0;
        __syncthreads();
        sh[t] += x;
        __syncthreads();
    }
    int r = sh[t] - tot;
    if (t == 255) partials[blk] = sh[t];
    #pragma unroll
    for (int j = 0; j < 4; j++) {
        if (i0 + j < CB) base[i0 + j] = r;
        r += v[j];
    }
}

__global__ void k_sc2(int* __restrict__ partials) {
    __shared__ int sh[128];
    int t = threadIdx.x;
    int v = (t < SC_BLKS) ? partials[t] : 0;
    sh[t] = v;
    __syncthreads();
    for (int o = 1; o < 128; o <<= 1) {
        int x = (t >= o) ? sh[t - o] : 0;
        __syncthreads();
        sh[t] += x;
        __syncthreads();
    }
    if (t < SC_BLKS) partials[t] = sh[t] - v;
}

__global__ __launch_bounds__(256) void k_sc3(int* __restrict__ base,
                                             const int* __restrict__ partials,
                                             int* __restrict__ offs) {
    int blk = blockIdx.x, t = threadIdx.x;
    int add = partials[blk];
    int i0 = blk * 1024 + t * 4;
    #pragma unroll
    for (int j = 0; j < 4; j++)
        if (i0 + j < CB) base[i0 + j] += add;
    if (blk == 0 && t == 0) { base[CB] = NEDGES; offs[NNODES] = NEDGES; }
}

// k_passA: scatter (src,dst) pairs into per-(bucket,block) sequential streams

__global__ __launch_bounds__(256) void k_passA(const int* __restrict__ src,
                                               const int* __restrict__ dst,
                                               const int* __restrict__ base,
                                               uint2* __restrict__ pairs) {
    __shared__ int cur[NB];
    int blk = blockIdx.x, t = threadIdx.x;
    for (int b = t; b < NB; b += 256) cur[b] = base[b * NBLK + blk];
    __syncthreads();
    int e0 = blk * EPB;
    for (int i = t; i < EPB; i += 256) {
        int s = src[e0 + i], d = dst[e0 + i];
        int p = atomicAdd(&cur[d >> 8], 1);
        pairs[p] = make_uint2((unsigned)s, (unsigned)d);
    }
}

// k_passB: per bucket, local histogram+scan -> offs + csr (L2-local scatter)

__global__ __launch_bounds__(256) void k_passB(const uint2* __restrict__ pairs,
                                               const int* __restrict__ base,
                                               int* __restrict__ offs,
                                               int* __restrict__ csr) {
    __shared__ int cnt[256], exc[256], cur[256];
    int b = blockIdx.x, t = threadIdx.x;
    int node0 = b << 8;
    int beg  = base[b * NBLK];          // bucket-major scan => contiguous range
    int endp = base[(b + 1) * NBLK];
    cnt[t] = 0;
    __syncthreads();
    for (int i = beg + t; i < endp; i += 256)
        atomicAdd(&cnt[pairs[i].y - node0], 1);
    __syncthreads();
    int v = cnt[t];
    exc[t] = v;
    __syncthreads();
    for (int o = 1; o < 256; o <<= 1) {
        int x = (t >= o) ? exc[t - o] : 0;
        __syncthreads();
        exc[t] += x;
        __syncthreads();
    }
    int e = exc[t] - v;
    if (node0 + t < NNODES) offs[node0 + t] = beg + e;
    cur[t] = beg + e;
    __syncthreads();
    for (int i = beg + t; i < endp; i += 256) {
        uint2 pr = pairs[i];
        int p = atomicAdd(&cur[pr.y - node0], 1);
        csr[p] = (int)pr.x;
    }
}

// ---------------- weight prep: W[K x N] fp32 -> WT[N x K] fp16 ----------------

__global__ void k_prepT(const float* __restrict__ W, _Float16* __restrict__ WT,
                        int K, int N) {
    int i = blockIdx.x * blockDim.x + threadIdx.x;
    if (i < K * N) {
        int n = i / K, k = i - n * K;
        WT[i] = (_Float16)W[(size_t)k * N + n];
    }
}

// ---- MFMA GEMM: C[N x 128](fp16) = A[N x K](fp32 or fp16) @ BT[128 x K](fp16) --

#define LDP 56

template<int K, bool IN16>
__global__ __launch_bounds__(256) void k_gemm_mfma(const void* __restrict__ Av,
                                                   const _Float16* __restrict__ BT,
                                                   _Float16* __restrict__ C) {
    __shared__ __align__(16) _Float16 As[64][LDP];
    __shared__ __align__(16) _Float16 Bs[128][LDP];
    int tid = threadIdx.x;
    int lane = tid & 63, wid = tid >> 6;
    int wr = wid >> 1, wc = wid & 1;          // wave grid 2x2
    int row0 = blockIdx.x * 64;

    f32x4 acc[2][4];
    #pragma unroll
    for (int mi = 0; mi < 2; mi++)
        #pragma unroll
        for (int ni = 0; ni < 4; ni++) acc[mi][ni] = (f32x4){0.f, 0.f, 0.f, 0.f};

    int srow = tid >> 2;            // 0..63
    int skoff = (tid & 3) * 8;      // 0,8,16,24
    int l15 = lane & 15;
    int kblk = (lane >> 4) * 8;

    for (int k0 = 0; k0 < K; k0 += 32) {
        int grow = row0 + srow;
        f16x8 ah = (f16x8){0, 0, 0, 0, 0, 0, 0, 0};
        if (grow < NNODES) {
            if constexpr (IN16) {
                const _Float16* A = (const _Float16*)Av;
                ah = *(const f16x8*)(A + (size_t)grow * K + k0 + skoff);
            } else {
                const float* A = (const float*)Av;
                const float* ap = A + (size_t)grow * K + k0 + skoff;
                float4 u0 = *(const float4*)ap;
                float4 u1 = *(const float4*)(ap + 4);
                ah[0] = (_Float16)u0.x; ah[1] = (_Float16)u0.y;
                ah[2] = (_Float16)u0.z; ah[3] = (_Float16)u0.w;
                ah[4] = (_Float16)u1.x; ah[5] = (_Float16)u1.y;
                ah[6] = (_Float16)u1.z; ah[7] = (_Float16)u1.w;
            }
        }
        *(f16x8*)&As[srow][skoff] = ah;
        #pragma unroll
        for (int p = 0; p < 2; p++) {
            int n = p * 64 + srow;
            *(f16x8*)&Bs[n][skoff] = *(const f16x8*)(BT + (size_t)n * K + k0 + skoff);
        }
        __syncthreads();
        f16x8 af[2], bf[4];
        #pragma unroll
        for (int mi = 0; mi < 2; mi++)
            af[mi] = *(const f16x8*)&As[wr * 32 + mi * 16 + l15][kblk];
        #pragma unroll
        for (int ni = 0; ni < 4; ni++)
            bf[ni] = *(const f16x8*)&Bs[wc * 64 + ni * 16 + l15][kblk];
        #pragma unroll
        for (int mi = 0; mi < 2; mi++)
            #pragma unroll
            for (int ni = 0; ni < 4; ni++)
                acc[mi][ni] = __builtin_amdgcn_mfma_f32_16x16x32_f16(
                    af[mi], bf[ni], acc[mi][ni], 0, 0, 0);
        __syncthreads();
    }
    #pragma unroll
    for (int mi = 0; mi < 2; mi++) {
        #pragma unroll
        for (int ni = 0; ni < 4; ni++) {
            int r = row0 + wr * 32 + mi * 16 + ((lane >> 4) << 2);
            int c = wc * 64 + ni * 16 + l15;
            #pragma unroll
            for (int j = 0; j < 4; j++) {
                if (r + j < NNODES)
                    C[(size_t)(r + j) * 128 + c] = (_Float16)acc[mi][ni][j];
            }
        }
    }
}

// ---------------- per-node attention scores (fp16 h, 2 cols/lane) --------------

__global__ void k_scores(const _Float16* __restrict__ h, const float* __restrict__ a_src,
                         const float* __restrict__ a_dst, float* __restrict__ ssrc,
                         float* __restrict__ sdst) {
    int lane = threadIdx.x & 63;
    int node = (blockIdx.x * blockDim.x + threadIdx.x) >> 6;
    if (node >= NNODES) return;
    const unsigned int* hrow = (const unsigned int*)h;
    float2 v = unpack_h2(hrow[(size_t)node * 64 + lane]);
    int c0 = lane * 2;
    float s1 = v.x * a_src[c0] + v.y * a_src[c0 + 1];
    float s2 = v.x * a_dst[c0] + v.y * a_dst[c0 + 1];
    s1 = waveReduceSum(s1);
    s2 = waveReduceSum(s2);
    if (lane == 0) { ssrc[node] = s1; sdst[node] = s2; }
}

// -------- segment-softmax aggregation (wave per dst node, fp16 h) --------------

__global__ void k_agg(const _Float16* __restrict__ h, const float* __restrict__ ssrc,
                      const float* __restrict__ sdst, const int* __restrict__ offs,
                      const int* __restrict__ csr, const float* __restrict__ bias,
                      _Float16* __restrict__ out, int do_relu) {
    int lane = threadIdx.x & 63;
    int node = (blockIdx.x * blockDim.x + threadIdx.x) >> 6;
    if (node >= NNODES) return;
    int beg = offs[node], end = offs[node + 1];
    float sd = sdst[node];
    float e_self = lrelu(ssrc[node] + sd);
    float m = e_self;
    for (int base = beg; base < end; base += 64) {
        int j = base + lane;
        float e = (j < end) ? lrelu(ssrc[csr[j]] + sd) : -3.4e38f;
        m = fmaxf(m, waveReduceMax(e));
    }
    const unsigned int* hrow = (const unsigned int*)h;
    float wself = __expf(e_self - m);
    float2 hv = unpack_h2(hrow[(size_t)node * 64 + lane]);
    float a0[4] = {wself * hv.x, 0.f, 0.f, 0.f};
    float a1[4] = {wself * hv.y, 0.f, 0.f, 0.f};
    float den_lane = 0.f;
    for (int base = beg; base < end; base += 64) {
        int j = base + lane;
        int s = 0; float w = 0.f;
        if (j < end) {
            s = csr[j];
            w = __expf(lrelu(ssrc[s] + sd) - m);
        }
        den_lane += w;
        int cnt = min(64, end - base);
        int t = 0;
        for (; t + 4 <= cnt; t += 4) {
            float w0 = __shfl(w, t, 64),     w1 = __shfl(w, t + 1, 64);
            float w2 = __shfl(w, t + 2, 64), w3 = __shfl(w, t + 3, 64);
            int   s0 = __shfl(s, t, 64),     s1 = __shfl(s, t + 1, 64);
            int   s2 = __shfl(s, t + 2, 64), s3 = __shfl(s, t + 3, 64);
            unsigned int u0 = hrow[(size_t)s0 * 64 + lane];
            unsigned int u1 = hrow[(size_t)s1 * 64 + lane];
            unsigned int u2 = hrow[(size_t)s2 * 64 + lane];
            unsigned int u3 = hrow[(size_t)s3 * 64 + lane];
            float2 p0 = unpack_h2(u0), p1 = unpack_h2(u1);
            float2 p2 = unpack_h2(u2), p3 = unpack_h2(u3);
            a0[0] += w0 * p0.x; a1[0] += w0 * p0.y;
            a0[1] += w1 * p1.x; a1[1] += w1 * p1.y;
            a0[2] += w2 * p2.x; a1[2] += w2 * p2.y;
            a0[3] += w3 * p3.x; a1[3] += w3 * p3.y;
        }
        for (; t < cnt; ++t) {
            float wj = __shfl(w, t, 64);
            int sj = __shfl(s, t, 64);
            float2 p = unpack_h2(hrow[(size_t)sj * 64 + lane]);
            a0[0] += wj * p.x; a1[0] += wj * p.y;
        }
    }
    float den = wself + waveReduceSum(den_lane);
    float inv = 1.f / den;
    int c0 = lane * 2;
    float r0 = (a0[0] + a0[1] + a0[2] + a0[3]) * inv + bias[c0];
    float r1 = (a1[0] + a1[1] + a1[2] + a1[3]) * inv + bias[c0 + 1];
    if (do_relu) { r0 = fmaxf(r0, 0.f); r1 = fmaxf(r1, 0.f); }
    ((unsigned int*)out)[(size_t)node * 64 + lane] = pack_h2(r0, r1);
}

// ---------------- final 128->3 matvec + softmax (fp16 h) -----------------------

__global__ void k_final(const _Float16* __restrict__ h, const float* __restrict__ Wo,
                        const float* __restrict__ bo, float* __restrict__ out) {
    int lane = threadIdx.x & 63;
    int node = (blockIdx.x * blockDim.x + threadIdx.x) >> 6;
    if (node >= NNODES) return;
    const unsigned int* hrow = (const unsigned int*)h;
    float2 v = unpack_h2(hrow[(size_t)node * 64 + lane]);
    int c0 = lane * 2, c1 = lane * 2 + 1;
    float p0 = v.x * Wo[c0 * NCLS + 0] + v.y * Wo[c1 * NCLS + 0];
    float p1 = v.x * Wo[c0 * NCLS + 1] + v.y * Wo[c1 * NCLS + 1];
    float p2 = v.x * Wo[c0 * NCLS + 2] + v.y * Wo[c1 * NCLS + 2];
    p0 = waveReduceSum(p0);
    p1 = waveReduceSum(p1);
    p2 = waveReduceSum(p2);
    if (lane == 0) {
        p0 += bo[0]; p1 += bo[1]; p2 += bo[2];
        float mm = fmaxf(p0, fmaxf(p1, p2));
        float e0 = __expf(p0 - mm), e1 = __expf(p1 - mm), e2 = __expf(p2 - mm);
        float inv = 1.f / (e0 + e1 + e2);
        out[(size_t)node * 3 + 0] = e0 * inv;
        out[(size_t)node * 3 + 1] = e1 * inv;
        out[(size_t)node * 3 + 2] = e2 * inv;
    }
}

// ---------------- launch ----------------

extern "C" void kernel_launch(void* const* d_in, const int* in_sizes, int n_in,
                              void* d_out, int out_size, void* d_ws, size_t ws_size,
                              hipStream_t stream) {
    const float* x   = (const float*)d_in[0];
    const int*   ei  = (const int*)d_in[1];
    const float* W1  = (const float*)d_in[2];
    const float* a1s = (const float*)d_in[3];
    const float* a1d = (const float*)d_in[4];
    const float* b1  = (const float*)d_in[5];
    const float* W2  = (const float*)d_in[6];
    const float* a2s = (const float*)d_in[7];
    const float* a2d = (const float*)d_in[8];
    const float* b2  = (const float*)d_in[9];
    const float* Wo  = (const float*)d_in[10];
    const float* bo  = (const float*)d_in[11];
    float* out = (float*)d_out;

    const int* esrc = ei;
    const int* edst = ei + NEDGES;

    char* ws = (char*)d_ws;
    size_t off = 0;
    auto alloc = [&](size_t bytes) -> void* {
        void* p = ws + off;
        off += (bytes + 255) & ~(size_t)255;
        return p;
    };
    _Float16*  buf0    = (_Float16*)alloc((size_t)NNODES * HID * 2);
    _Float16*  buf1    = (_Float16*)alloc((size_t)NNODES * HID * 2);
    float*     ssrc    = (float*)alloc((size_t)NNODES * 4);
    float*     sdst    = (float*)alloc((size_t)NNODES * 4);
    int*       offs    = (int*)alloc((size_t)(NNODES + 1) * 4);
    int*       counts  = (int*)alloc((size_t)CB * 4);
    int*       base    = (int*)alloc((size_t)(CB + 1) * 4);
    int*       partial = (int*)alloc(256 * 4);
    uint2*     pairs   = (uint2*)alloc((size_t)NEDGES * 8);
    int*       csr     = (int*)alloc((size_t)NEDGES * 4);
    _Float16*  w1t     = (_Float16*)alloc((size_t)HID * NIN * 2);
    _Float16*  w2t     = (_Float16*)alloc((size_t)HID * HID * 2);
    if (off > ws_size) return;  // workspace too small -> loud correctness failure

    // ---- weight prep (fp16, transposed) ----
    k_prepT<<<(NIN * HID + 255) / 256, 256, 0, stream>>>(W1, w1t, NIN, HID);
    k_prepT<<<(HID * HID + 255) / 256, 256, 0, stream>>>(W2, w2t, HID, HID);

    // ---- CSR build via two-level bucket sort (hierarchical scan) ----
    k_hist0<<<NBLK, 256, 0, stream>>>(edst, counts);
    k_sc1<<<SC_BLKS, 256, 0, stream>>>(counts, base, partial);
    k_sc2<<<1, 128, 0, stream>>>(partial);
    k_sc3<<<SC_BLKS, 256, 0, stream>>>(base, partial, offs);
    k_passA<<<NBLK, 256, 0, stream>>>(esrc, edst, base, pairs);
    k_passB<<<NB, 256, 0, stream>>>(pairs, base, offs, csr);

    int mgrid = (NNODES + 63) / 64;   // 1563 blocks
    int wgrid = NNODES / 4;           // wave-per-node kernels, 4 waves/block

    // ---- layer 1 ----
    k_gemm_mfma<NIN, false><<<mgrid, 256, 0, stream>>>(x, w1t, buf0);
    k_scores<<<wgrid, 256, 0, stream>>>(buf0, a1s, a1d, ssrc, sdst);
    k_agg<<<wgrid, 256, 0, stream>>>(buf0, ssrc, sdst, offs, csr, b1, buf1, 1);

    // ---- layer 2 ----
    k_gemm_mfma<HID, true><<<mgrid, 256, 0, stream>>>(buf1, w2t, buf0);
    k_scores<<<wgrid, 256, 0, stream>>>(buf0, a2s, a2d, ssrc, sdst);
    k_agg<<<wgrid, 256, 0, stream>>>(buf0, ssrc, sdst, offs, csr, b2, buf1, 1);

    // ---- output head ----
    k_final<<<wgrid, 256, 0, stream>>>(buf1, Wo, bo, out);
}

// Round 15
// 473.252 us; speedup vs baseline: 1.9841x; 1.0024x over previous
//
#include <hip/hip_runtime.h>
#include <math.h>

#define NNODES 100000
#define NEDGES 1600000
#define NIN 256
#define HID 128
#define NCLS 3

// ---- bucket-sort CSR build parameters ----
#define NB   391      // ceil(NNODES/256) buckets of 256 nodes
#define NBLK 200      // pass-A blocks
#define EPB  8000     // edges per block (NBLK*EPB == NEDGES)
#define CB   (NB*NBLK)
#define SC_BLKS 77    // ceil(CB/1024)

using f16x8 = __attribute__((ext_vector_type(8))) _Float16;
using f16x2 = __attribute__((ext_vector_type(2))) _Float16;
using f32x4 = __attribute__((ext_vector_type(4))) float;

__device__ __forceinline__ float lrelu(float x) { return x > 0.f ? x : 0.2f * x; }

__device__ __forceinline__ float waveReduceSum(float v) {
    #pragma unroll
    for (int o = 32; o > 0; o >>= 1) v += __shfl_xor(v, o, 64);
    return v;
}
__device__ __forceinline__ float waveReduceMax(float v) {
    #pragma unroll
    for (int o = 32; o > 0; o >>= 1) v = fmaxf(v, __shfl_xor(v, o, 64));
    return v;
}

__device__ __forceinline__ float2 unpack_h2(unsigned int u) {
    union { unsigned int u; f16x2 h; } cv; cv.u = u;
    return make_float2((float)cv.h[0], (float)cv.h[1]);
}
__device__ __forceinline__ unsigned int pack_h2(float x, float y) {
    union { unsigned int u; f16x2 h; } cv;
    cv.h[0] = (_Float16)x; cv.h[1] = (_Float16)y;
    return cv.u;
}

// ---------------- CSR build: two-level bucket sort ----------------

__global__ __launch_bounds__(256) void k_hist0(const int* __restrict__ dst,
                                               int* __restrict__ counts) {
    __shared__ int h[NB];
    int blk = blockIdx.x, t = threadIdx.x;
    for (int b = t; b < NB; b += 256) h[b] = 0;
    __syncthreads();
    int e0 = blk * EPB;
    for (int i = t; i < EPB; i += 256)
        atomicAdd(&h[dst[e0 + i] >> 8], 1);
    __syncthreads();
    for (int b = t; b < NB; b += 256) counts[b * NBLK + blk] = h[b];  // bucket-major
}

__global__ __launch_bounds__(256) void k_sc1(const int* __restrict__ counts,
                                             int* __restrict__ base,
                                             int* __restrict__ partials) {
    __shared__ int sh[256];
    int blk = blockIdx.x, t = threadIdx.x;
    int i0 = blk * 1024 + t * 4;
    int v[4]; int tot = 0;
    #pragma unroll
    for (int j = 0; j < 4; j++) {
        v[j] = (i0 + j < CB) ? counts[i0 + j] : 0;
        tot += v[j];
    }
    sh[t] = tot;
    __syncthreads();
    for (int o = 1; o < 256; o <<= 1) {
        int x = (t >= o) ? sh[t - o] : 0;
        __syncthreads();
        sh[t] += x;
        __syncthreads();
    }
    int r = sh[t] - tot;
    if (t == 255) partials[blk] = sh[t];
    #pragma unroll
    for (int j = 0; j < 4; j++) {
        if (i0 + j < CB) base[i0 + j] = r;
        r += v[j];
    }
}

__global__ void k_sc2(int* __restrict__ partials) {
    __shared__ int sh[128];
    int t = threadIdx.x;
    int v = (t < SC_BLKS) ? partials[t] : 0;
    sh[t] = v;
    __syncthreads();
    for (int o = 1; o < 128; o <<= 1) {
        int x = (t >= o) ? sh[t - o] : 0;
        __syncthreads();
        sh[t] += x;
        __syncthreads();
    }
    if (t < SC_BLKS) partials[t] = sh[t] - v;
}

__global__ __launch_bounds__(256) void k_sc3(int* __restrict__ base,
                                             const int* __restrict__ partials,
                                             int* __restrict__ offs) {
    int blk = blockIdx.x, t = threadIdx.x;
    int add = partials[blk];
    int i0 = blk * 1024 + t * 4;
    #pragma unroll
    for (int j = 0; j < 4; j++)
        if (i0 + j < CB) base[i0 + j] += add;
    if (blk == 0 && t == 0) { base[CB] = NEDGES; offs[NNODES] = NEDGES; }
}

__global__ __launch_bounds__(256) void k_passA(const int* __restrict__ src,
                                               const int* __restrict__ dst,
                                               const int* __restrict__ base,
                                               uint2* __restrict__ pairs) {
    __shared__ int cur[NB];
    int blk = blockIdx.x, t = threadIdx.x;
    for (int b = t; b < NB; b += 256) cur[b] = base[b * NBLK + blk];
    __syncthreads();
    int e0 = blk * EPB;
    for (int i = t; i < EPB; i += 256) {
        int s = src[e0 + i], d = dst[e0 + i];
        int p = atomicAdd(&cur[d >> 8], 1);
        pairs[p] = make_uint2((unsigned)s, (unsigned)d);
    }
}

__global__ __launch_bounds__(256) void k_passB(const uint2* __restrict__ pairs,
                                               const int* __restrict__ base,
                                               int* __restrict__ offs,
                                               int* __restrict__ csr) {
    __shared__ int cnt[256], exc[256], cur[256];
    int b = blockIdx.x, t = threadIdx.x;
    int node0 = b << 8;
    int beg  = base[b * NBLK];          // bucket-major scan => contiguous range
    int endp = base[(b + 1) * NBLK];
    cnt[t] = 0;
    __syncthreads();
    for (int i = beg + t; i < endp; i += 256)
        atomicAdd(&cnt[pairs[i].y - node0], 1);
    __syncthreads();
    int v = cnt[t];
    exc[t] = v;
    __syncthreads();
    for (int o = 1; o < 256; o <<= 1) {
        int x = (t >= o) ? exc[t - o] : 0;
        __syncthreads();
        exc[t] += x;
        __syncthreads();
    }
    int e = exc[t] - v;
    if (node0 + t < NNODES) offs[node0 + t] = beg + e;
    cur[t] = beg + e;
    __syncthreads();
    for (int i = beg + t; i < endp; i += 256) {
        uint2 pr = pairs[i];
        int p = atomicAdd(&cur[pr.y - node0], 1);
        csr[p] = (int)pr.x;
    }
}

// ---------------- weight prep: W[K x N] fp32 -> WT[N x K] fp16 ----------------

__global__ void k_prepT(const float* __restrict__ W, _Float16* __restrict__ WT,
                        int K, int N) {
    int i = blockIdx.x * blockDim.x + threadIdx.x;
    if (i < K * N) {
        int n = i / K, k = i - n * K;
        WT[i] = (_Float16)W[(size_t)k * N + n];
    }
}

// ---- MFMA GEMM: C[N x 128](fp16) = A[N x K](fp32 or fp16) @ BT[128 x K](fp16) --

#define LDP 56

template<int K, bool IN16>
__global__ __launch_bounds__(256) void k_gemm_mfma(const void* __restrict__ Av,
                                                   const _Float16* __restrict__ BT,
                                                   _Float16* __restrict__ C) {
    __shared__ __align__(16) _Float16 As[64][LDP];
    __shared__ __align__(16) _Float16 Bs[128][LDP];
    int tid = threadIdx.x;
    int lane = tid & 63, wid = tid >> 6;
    int wr = wid >> 1, wc = wid & 1;          // wave grid 2x2
    int row0 = blockIdx.x * 64;

    f32x4 acc[2][4];
    #pragma unroll
    for (int mi = 0; mi < 2; mi++)
        #pragma unroll
        for (int ni = 0; ni < 4; ni++) acc[mi][ni] = (f32x4){0.f, 0.f, 0.f, 0.f};

    int srow = tid >> 2;            // 0..63
    int skoff = (tid & 3) * 8;      // 0,8,16,24
    int l15 = lane & 15;
    int kblk = (lane >> 4) * 8;

    for (int k0 = 0; k0 < K; k0 += 32) {
        int grow = row0 + srow;
        f16x8 ah = (f16x8){0, 0, 0, 0, 0, 0, 0, 0};
        if (grow < NNODES) {
            if constexpr (IN16) {
                const _Float16* A = (const _Float16*)Av;
                ah = *(const f16x8*)(A + (size_t)grow * K + k0 + skoff);
            } else {
                const float* A = (const float*)Av;
                const float* ap = A + (size_t)grow * K + k0 + skoff;
                float4 u0 = *(const float4*)ap;
                float4 u1 = *(const float4*)(ap + 4);
                ah[0] = (_Float16)u0.x; ah[1] = (_Float16)u0.y;
                ah[2] = (_Float16)u0.z; ah[3] = (_Float16)u0.w;
                ah[4] = (_Float16)u1.x; ah[5] = (_Float16)u1.y;
                ah[6] = (_Float16)u1.z; ah[7] = (_Float16)u1.w;
            }
        }
        *(f16x8*)&As[srow][skoff] = ah;
        #pragma unroll
        for (int p = 0; p < 2; p++) {
            int n = p * 64 + srow;
            *(f16x8*)&Bs[n][skoff] = *(const f16x8*)(BT + (size_t)n * K + k0 + skoff);
        }
        __syncthreads();
        f16x8 af[2], bf[4];
        #pragma unroll
        for (int mi = 0; mi < 2; mi++)
            af[mi] = *(const f16x8*)&As[wr * 32 + mi * 16 + l15][kblk];
        #pragma unroll
        for (int ni = 0; ni < 4; ni++)
            bf[ni] = *(const f16x8*)&Bs[wc * 64 + ni * 16 + l15][kblk];
        #pragma unroll
        for (int mi = 0; mi < 2; mi++)
            #pragma unroll
            for (int ni = 0; ni < 4; ni++)
                acc[mi][ni] = __builtin_amdgcn_mfma_f32_16x16x32_f16(
                    af[mi], bf[ni], acc[mi][ni], 0, 0, 0);
        __syncthreads();
    }
    #pragma unroll
    for (int mi = 0; mi < 2; mi++) {
        #pragma unroll
        for (int ni = 0; ni < 4; ni++) {
            int r = row0 + wr * 32 + mi * 16 + ((lane >> 4) << 2);
            int c = wc * 64 + ni * 16 + l15;
            #pragma unroll
            for (int j = 0; j < 4; j++) {
                if (r + j < NNODES)
                    C[(size_t)(r + j) * 128 + c] = (_Float16)acc[mi][ni][j];
            }
        }
    }
}

// ---------------- per-node attention scores (fp16 h, 2 cols/lane) --------------

__global__ void k_scores(const _Float16* __restrict__ h, const float* __restrict__ a_src,
                         const float* __restrict__ a_dst, float* __restrict__ ssrc,
                         float* __restrict__ sdst) {
    int lane = threadIdx.x & 63;
    int node = (blockIdx.x * blockDim.x + threadIdx.x) >> 6;
    if (node >= NNODES) return;
    const unsigned int* hrow = (const unsigned int*)h;
    float2 v = unpack_h2(hrow[(size_t)node * 64 + lane]);
    int c0 = lane * 2;
    float s1 = v.x * a_src[c0] + v.y * a_src[c0 + 1];
    float s2 = v.x * a_dst[c0] + v.y * a_dst[c0 + 1];
    s1 = waveReduceSum(s1);
    s2 = waveReduceSum(s2);
    if (lane == 0) { ssrc[node] = s1; sdst[node] = s2; }
}

// -------- segment-softmax aggregation (wave per dst node, fp16 h) --------------
// Pass 2 processes 2 edges per wave-iteration: lanes 0-31 take even edges,
// lanes 32-63 odd edges; each lane gathers uint2 (4 cols) so one VMEM inst
// covers two full h rows. Cross-half merge via shfl_xor(32) at the end.

__global__ void k_agg(const _Float16* __restrict__ h, const float* __restrict__ ssrc,
                      const float* __restrict__ sdst, const int* __restrict__ offs,
                      const int* __restrict__ csr, const float* __restrict__ bias,
                      _Float16* __restrict__ out, int do_relu) {
    int lane = threadIdx.x & 63;
    int node = (blockIdx.x * blockDim.x + threadIdx.x) >> 6;
    if (node >= NNODES) return;
    int half = lane >> 5, hl = lane & 31;
    int beg = offs[node], end = offs[node + 1];
    float sd = sdst[node];
    float e_self = lrelu(ssrc[node] + sd);
    // pass 1: segment max (self-loop handled analytically)
    float m = e_self;
    for (int base = beg; base < end; base += 64) {
        int j = base + lane;
        float e = (j < end) ? lrelu(ssrc[csr[j]] + sd) : -3.4e38f;
        m = fmaxf(m, waveReduceMax(e));
    }
    // pass 2: exp weights + weighted feature accumulation (4 cols/lane, 2 edges/iter)
    const uint2* hrow2 = (const uint2*)h;
    float accA[4] = {0.f, 0.f, 0.f, 0.f};
    float accB[4] = {0.f, 0.f, 0.f, 0.f};
    float den_lane = 0.f;
    for (int base = beg; base < end; base += 64) {
        int j = base + lane;
        int s = 0; float w = 0.f;          // w=0 for j>=end => shfl'd terms add 0
        if (j < end) {
            s = csr[j];
            w = __expf(lrelu(ssrc[s] + sd) - m);
        }
        den_lane += w;
        int cnt = min(64, end - base);
        int npair = (cnt + 1) >> 1;
        int p = 0;
        for (; p + 2 <= npair; p += 2) {
            int i0 = 2 * p + half, i1 = 2 * p + 2 + half;
            float w0 = __shfl(w, i0, 64); int s0 = __shfl(s, i0, 64);
            float w1 = __shfl(w, i1, 64); int s1 = __shfl(s, i1, 64);
            uint2 u0 = hrow2[(size_t)s0 * 32 + hl];
            uint2 u1 = hrow2[(size_t)s1 * 32 + hl];
            float2 q00 = unpack_h2(u0.x), q01 = unpack_h2(u0.y);
            float2 q10 = unpack_h2(u1.x), q11 = unpack_h2(u1.y);
            accA[0] += w0 * q00.x; accA[1] += w0 * q00.y;
            accA[2] += w0 * q01.x; accA[3] += w0 * q01.y;
            accB[0] += w1 * q10.x; accB[1] += w1 * q10.y;
            accB[2] += w1 * q11.x; accB[3] += w1 * q11.y;
        }
        for (; p < npair; ++p) {
            int i0 = 2 * p + half;
            float w0 = __shfl(w, i0, 64); int s0 = __shfl(s, i0, 64);
            uint2 u0 = hrow2[(size_t)s0 * 32 + hl];
            float2 q00 = unpack_h2(u0.x), q01 = unpack_h2(u0.y);
            accA[0] += w0 * q00.x; accA[1] += w0 * q00.y;
            accA[2] += w0 * q01.x; accA[3] += w0 * q01.y;
        }
    }
    float acc[4];
    #pragma unroll
    for (int k = 0; k < 4; k++) {
        acc[k] = accA[k] + accB[k];
        acc[k] += __shfl_xor(acc[k], 32, 64);   // merge even/odd halves
    }
    // self term (after merge; both halves hold full edge sums)
    float wself = __expf(e_self - m);
    uint2 uself = hrow2[(size_t)node * 32 + hl];
    float2 hs0 = unpack_h2(uself.x), hs1 = unpack_h2(uself.y);
    acc[0] += wself * hs0.x; acc[1] += wself * hs0.y;
    acc[2] += wself * hs1.x; acc[3] += wself * hs1.y;
    float den = wself + waveReduceSum(den_lane);
    float inv = 1.f / den;
    if (half == 0) {
        const float4* b4 = (const float4*)bias;
        float4 bb = b4[hl];
        float r0 = acc[0] * inv + bb.x;
        float r1 = acc[1] * inv + bb.y;
        float r2 = acc[2] * inv + bb.z;
        float r3 = acc[3] * inv + bb.w;
        if (do_relu) {
            r0 = fmaxf(r0, 0.f); r1 = fmaxf(r1, 0.f);
            r2 = fmaxf(r2, 0.f); r3 = fmaxf(r3, 0.f);
        }
        uint2 o;
        o.x = pack_h2(r0, r1);
        o.y = pack_h2(r2, r3);
        ((uint2*)out)[(size_t)node * 32 + hl] = o;
    }
}

// ---------------- final 128->3 matvec + softmax (fp16 h) -----------------------

__global__ void k_final(const _Float16* __restrict__ h, const float* __restrict__ Wo,
                        const float* __restrict__ bo, float* __restrict__ out) {
    int lane = threadIdx.x & 63;
    int node = (blockIdx.x * blockDim.x + threadIdx.x) >> 6;
    if (node >= NNODES) return;
    const unsigned int* hrow = (const unsigned int*)h;
    float2 v = unpack_h2(hrow[(size_t)node * 64 + lane]);
    int c0 = lane * 2, c1 = lane * 2 + 1;
    float p0 = v.x * Wo[c0 * NCLS + 0] + v.y * Wo[c1 * NCLS + 0];
    float p1 = v.x * Wo[c0 * NCLS + 1] + v.y * Wo[c1 * NCLS + 1];
    float p2 = v.x * Wo[c0 * NCLS + 2] + v.y * Wo[c1 * NCLS + 2];
    p0 = waveReduceSum(p0);
    p1 = waveReduceSum(p1);
    p2 = waveReduceSum(p2);
    if (lane == 0) {
        p0 += bo[0]; p1 += bo[1]; p2 += bo[2];
        float mm = fmaxf(p0, fmaxf(p1, p2));
        float e0 = __expf(p0 - mm), e1 = __expf(p1 - mm), e2 = __expf(p2 - mm);
        float inv = 1.f / (e0 + e1 + e2);
        out[(size_t)node * 3 + 0] = e0 * inv;
        out[(size_t)node * 3 + 1] = e1 * inv;
        out[(size_t)node * 3 + 2] = e2 * inv;
    }
}

// ---------------- launch ----------------

extern "C" void kernel_launch(void* const* d_in, const int* in_sizes, int n_in,
                              void* d_out, int out_size, void* d_ws, size_t ws_size,
                              hipStream_t stream) {
    const float* x   = (const float*)d_in[0];
    const int*   ei  = (const int*)d_in[1];
    const float* W1  = (const float*)d_in[2];
    const float* a1s = (const float*)d_in[3];
    const float* a1d = (const float*)d_in[4];
    const float* b1  = (const float*)d_in[5];
    const float* W2  = (const float*)d_in[6];
    const float* a2s = (const float*)d_in[7];
    const float* a2d = (const float*)d_in[8];
    const float* b2  = (const float*)d_in[9];
    const float* Wo  = (const float*)d_in[10];
    const float* bo  = (const float*)d_in[11];
    float* out = (float*)d_out;

    const int* esrc = ei;
    const int* edst = ei + NEDGES;

    char* ws = (char*)d_ws;
    size_t off = 0;
    auto alloc = [&](size_t bytes) -> void* {
        void* p = ws + off;
        off += (bytes + 255) & ~(size_t)255;
        return p;
    };
    _Float16*  buf0    = (_Float16*)alloc((size_t)NNODES * HID * 2);
    _Float16*  buf1    = (_Float16*)alloc((size_t)NNODES * HID * 2);
    float*     ssrc    = (float*)alloc((size_t)NNODES * 4);
    float*     sdst    = (float*)alloc((size_t)NNODES * 4);
    int*       offs    = (int*)alloc((size_t)(NNODES + 1) * 4);
    int*       counts  = (int*)alloc((size_t)CB * 4);
    int*       base    = (int*)alloc((size_t)(CB + 1) * 4);
    int*       partial = (int*)alloc(256 * 4);
    uint2*     pairs   = (uint2*)alloc((size_t)NEDGES * 8);
    int*       csr     = (int*)alloc((size_t)NEDGES * 4);
    _Float16*  w1t     = (_Float16*)alloc((size_t)HID * NIN * 2);
    _Float16*  w2t     = (_Float16*)alloc((size_t)HID * HID * 2);
    if (off > ws_size) return;  // workspace too small -> loud correctness failure

    // ---- weight prep (fp16, transposed) ----
    k_prepT<<<(NIN * HID + 255) / 256, 256, 0, stream>>>(W1, w1t, NIN, HID);
    k_prepT<<<(HID * HID + 255) / 256, 256, 0, stream>>>(W2, w2t, HID, HID);

    // ---- CSR build via two-level bucket sort (hierarchical scan) ----
    k_hist0<<<NBLK, 256, 0, stream>>>(edst, counts);
    k_sc1<<<SC_BLKS, 256, 0, stream>>>(counts, base, partial);
    k_sc2<<<1, 128, 0, stream>>>(partial);
    k_sc3<<<SC_BLKS, 256, 0, stream>>>(base, partial, offs);
    k_passA<<<NBLK, 256, 0, stream>>>(esrc, edst, base, pairs);
    k_passB<<<NB, 256, 0, stream>>>(pairs, base, offs, csr);

    int mgrid = (NNODES + 63) / 64;   // 1563 blocks
    int wgrid = NNODES / 4;           // wave-per-node kernels, 4 waves/block

    // ---- layer 1 ----
    k_gemm_mfma<NIN, false><<<mgrid, 256, 0, stream>>>(x, w1t, buf0);
    k_scores<<<wgrid, 256, 0, stream>>>(buf0, a1s, a1d, ssrc, sdst);
    k_agg<<<wgrid, 256, 0, stream>>>(buf0, ssrc, sdst, offs, csr, b1, buf1, 1);

    // ---- layer 2 ----
    k_gemm_mfma<HID, true><<<mgrid, 256, 0, stream>>>(buf1, w2t, buf0);
    k_scores<<<wgrid, 256, 0, stream>>>(buf0, a2s, a2d, ssrc, sdst);
    k_agg<<<wgrid, 256, 0, stream>>>(buf0, ssrc, sdst, offs, csr, b2, buf1, 1);

    // ---- output head ----
    k_final<<<wgrid, 256, 0, stream>>>(buf1, Wo, bo, out);
}